// Round 4
// baseline (9017.635 us; speedup 1.0000x reference)
//
#include <hip/hip_runtime.h>
#include <math.h>

// Problem constants
#define TT 512
#define BB 64
#define EE 300
#define HD 256
#define KK 20
#define NG 1024        // gate rows per direction
#define RG 4           // row-groups per direction
#define RPB 16         // rows per block
#define DPB 32         // dims per block
#define HS 260         // LDS h row stride (floats), padded
#define HOFF (128 * 256)                  // W slice: 128 gate-rows x 256 k = 128 KB
#define LDS_FLOATS (HOFF + RPB * HS)      // 36928 floats = 147712 B

// Relaxed agent-scope atomics = cache-bypassing LLC ops (no fences anywhere;
// W/P stay cache-resident). Proven correct across prior rounds (absmax 0).
__device__ __forceinline__ int ldg_llc_i(const int* p) {
    return __hip_atomic_load(p, __ATOMIC_RELAXED, __HIP_MEMORY_SCOPE_AGENT);
}
__device__ __forceinline__ void stg_llc_i(int* p, int v) {
    __hip_atomic_store(p, v, __ATOMIC_RELAXED, __HIP_MEMORY_SCOPE_AGENT);
}
__device__ __forceinline__ unsigned long long ldg_llc_u64(const unsigned long long* p) {
    return __hip_atomic_load(p, __ATOMIC_RELAXED, __HIP_MEMORY_SCOPE_AGENT);
}
__device__ __forceinline__ void stg_llc_f(float* p, float v) {
    __hip_atomic_store(p, v, __ATOMIC_RELAXED, __HIP_MEMORY_SCOPE_AGENT);
}

// branchless 4-way select (compile-time value indices only)
__device__ __forceinline__ float mux4(int t, float x0, float x1, float x2, float x3) {
    const bool b0 = (t & 1) != 0, b1 = (t & 2) != 0;
    const float lo = b0 ? x1 : x0;
    const float hi = b0 ? x3 : x2;
    return b1 ? hi : lo;
}

// ============================================================
// K1: fused embedding-gather + input projection GEMM (fp32)
// P layout: [slot][row(64)][gate(1024)] (gate innermost).  (unchanged, proven)
// ============================================================
__global__ __launch_bounds__(256) void proj_kernel(
    const int* __restrict__ sentence, const float* __restrict__ embed,
    const float* __restrict__ Wf_ih, const float* __restrict__ bf,
    const float* __restrict__ Wb_ih, const float* __restrict__ bb,
    float* __restrict__ Pf, float* __restrict__ Pb, int t0f, int t0b)
{
    __shared__ float As[32][BB];
    __shared__ float Ws[32][64];
    const int s   = blockIdx.x;
    const int gb  = blockIdx.y;
    const int dir = gb >> 4;
    const int g0  = (gb & 15) * 64;
    const int tg  = dir ? (t0b + s) : (t0f + s);
    const int tid = threadIdx.x;
    const int tx = tid & 15, ty = tid >> 4;

    const int lrow = tid >> 2;
    const int kq   = tid & 3;
    const int word = sentence[lrow * TT + tg];
    const float* arow = embed + (size_t)word * EE;
    const float* Wih  = dir ? Wb_ih : Wf_ih;
    const float* bias = dir ? bb : bf;
    const float* wrow = Wih + (size_t)(g0 + lrow) * EE;

    float acc[4][4] = {};
    for (int k0 = 0; k0 < EE; k0 += 32) {
        __syncthreads();
        #pragma unroll
        for (int u = 0; u < 8; ++u) {
            const int k  = kq * 8 + u;
            const int kk = k0 + k;
            const bool ok = (kk < EE);
            As[k][lrow] = ok ? arow[kk] : 0.f;
            Ws[k][lrow] = ok ? wrow[kk] : 0.f;
        }
        __syncthreads();
        #pragma unroll
        for (int k = 0; k < 32; ++k) {
            const float4 a = *(const float4*)&As[k][ty * 4];
            const float4 w = *(const float4*)&Ws[k][tx * 4];
            acc[0][0] += a.x*w.x; acc[0][1] += a.x*w.y; acc[0][2] += a.x*w.z; acc[0][3] += a.x*w.w;
            acc[1][0] += a.y*w.x; acc[1][1] += a.y*w.y; acc[1][2] += a.y*w.z; acc[1][3] += a.y*w.w;
            acc[2][0] += a.z*w.x; acc[2][1] += a.z*w.y; acc[2][2] += a.z*w.z; acc[2][3] += a.z*w.w;
            acc[3][0] += a.w*w.x; acc[3][1] += a.w*w.y; acc[3][2] += a.w*w.z; acc[3][3] += a.w*w.w;
        }
    }
    float* Pd = (dir ? Pb : Pf) + (size_t)s * BB * NG;
    const float4 bv = *(const float4*)&bias[g0 + tx * 4];
    #pragma unroll
    for (int i = 0; i < 4; ++i) {
        float4 v;
        v.x = acc[i][0] + bv.x; v.y = acc[i][1] + bv.y;
        v.z = acc[i][2] + bv.z; v.w = acc[i][3] + bv.w;
        *(float4*)(Pd + (size_t)(ty * 4 + i) * NG + g0 + tx * 4) = v;
    }
}

// ============================================================
// K2: 2D-partitioned bidirectional LSTM, BROADCAST-W GEMV.
// 64 blocks x 256 threads. blk&7 = domain (dir*4 + row-group i); dim-group
// j = blk>>3. Block owns 16 rows x 32 dims. W slice (128 gate-rows x 256 k,
// 128 KB) preloaded to LDS once (layout [(dloc*4+g)][k], stride 256).
//
// Wave w covers dims j*32 + w*8 .. +7. Lane = (r = lane>>2 row 0..15,
// s = lane&3 k-class). Thread's k set: quads q ≡ s (mod 4), i.e. k = 16t+4s,
// t=0..15 — held in 16 float4 VGPRs after staging. GEMV: 512 ds_read_b128 of
// W where the address depends ONLY on s -> 4 distinct 16B quads per wave-read
// (64 B vs 1 KB): LDS BW drops ~12x vs R0 (the measured R0 wall). Partial
// acc[32] (8 dims x 4 gates, all 16 rows' worth... each lane: its row r,
// all 32 gate-rows of its wave) reduced over the 4 s-lanes via intra-quad
// __shfl_xor(1,2) = DPP (pure VALU, no LDS). Lane then owns (row r, dims
// 2s,2s+1): mux4 extract -> cell math -> publish.
// Exchange protocol / staging / flags / parity: verbatim R0 (proven).
// ============================================================
__global__ __launch_bounds__(256, 1) void lstm_kernel(
    const float* __restrict__ Pf, const float* __restrict__ Pb,
    const float* __restrict__ Wf_hh, const float* __restrict__ Wb_hh,
    const int* __restrict__ lengths,
    float* __restrict__ HF, float* __restrict__ HB,
    float* __restrict__ hx,      // [parity][dir][rg][dim 256][row 16]
    float* __restrict__ cbuf,    // [dir][row 64][dim 256]
    int* __restrict__ flags,     // [dir*4+rg][16] (one 64B line per domain)
    int step0, int nsteps)
{
    extern __shared__ float lds[];
    const int blk    = blockIdx.x;
    const int domain = blk & 7;          // dir*4 + i  (XCD residue)
    const int j      = blk >> 3;         // dim-group 0..7
    const int dir    = domain >> 2;
    const int i      = domain & 3;       // row-group
    const int tid    = threadIdx.x;
    const int w      = tid >> 6;         // wave 0..3 (dim octet)
    const int lane   = tid & 63;
    const int r      = lane >> 2;        // row 0..15
    const int s      = lane & 3;         // k-class 0..3
    const int dwb    = j * DPB + w * 8;  // wave's dim base
    const int dgo    = dwb + 2 * s;      // this lane's even output dim
    const int grow   = i * RPB + r;      // global batch row

    const float* Whh = dir ? Wb_hh : Wf_hh;
    const float* P   = dir ? Pb : Pf;
    float* Hout = dir ? HB : HF;
    int* myflags = flags + domain * 16;
    const int len = lengths[grow];

    // ---- W preload: lds[(dloc*4+g)*256 + k] = Whh[g*256 + j*32 + dloc][k]
    // coalesced 1KB rows; one-time cost.
    for (int e = tid; e < 128 * 256; e += 256) {
        const int glx = e >> 8;          // 0..127 local gate-row (dloc*4+g)
        const int k   = e & 255;
        const int dl2 = glx >> 2, g = glx & 3;
        lds[glx * 256 + k] = Whh[(size_t)(g * HD + j * DPB + dl2) * HD + k];
    }

    // ---- cell state: this lane's (row, dims 2s,2s+1)
    const float2 cin = *(const float2*)&cbuf[((size_t)dir * BB + grow) * HD + dgo];
    float c0 = cin.x, c1 = cin.y;
    __syncthreads();   // W preload visible before first GEMV

    for (int u = 0; u < nsteps; ++u) {
        const int gs   = step0 + u;
        const int p    = dir ? (TT - 1 - gs) : gs;
        const int slot = dir ? (nsteps - 1 - u) : u;

        // P terms (h-independent): 8 loads issued before the wait
        const float* Pp = P + (size_t)slot * BB * NG + (size_t)grow * NG + dwb;
        const int s2 = 2 * s;
        const float pi0 = Pp[s2],       pi1 = Pp[s2 + 1];
        const float pf0 = Pp[256 + s2], pf1 = Pp[256 + s2 + 1];
        const float pg0 = Pp[512 + s2], pg1 = Pp[512 + s2 + 1];
        const float po0 = Pp[768 + s2], po1 = Pp[768 + s2 + 1];

        // wait: all 8 peers (dim-groups) of this domain finished step gs-1
        if (tid < 64) {
            const int* fl = myflags + (tid & 7);
            while (true) {
                const int v = ldg_llc_i(fl);
                if (__all(v >= gs)) break;
            }
        }
        __syncthreads();

        // stage h slice (16 KB) LLC -> LDS, transposing [k][r] -> [r][k]  (verbatim R0)
        {
            const unsigned long long* src = (const unsigned long long*)
                (hx + ((size_t)(((gs + 1) & 1) * 2 + dir) * RG + i) * (HD * RPB));
            const int kbase = tid >> 3, rp = tid & 7;
            #pragma unroll
            for (int it = 0; it < 8; ++it) {
                const int k = kbase + 32 * it;
                const unsigned long long v = ldg_llc_u64(&src[k * 8 + rp]);
                union { unsigned long long uu; float f[2]; } cv; cv.uu = v;
                lds[HOFF + (2 * rp) * HS + k]     = cv.f[0];
                lds[HOFF + (2 * rp + 1) * HS + k] = cv.f[1];
            }
        }
        __syncthreads();

        // h slice for this lane (row r, quads ≡ s mod 4) -> 16 float4 regs
        float4 h4[16];
        {
            const float* hb2 = lds + HOFF + r * HS + 4 * s;
            #pragma unroll
            for (int t = 0; t < 16; ++t) h4[t] = *(const float4*)(hb2 + 16 * t);
        }

        // GEMV: 512 broadcast W-reads (addr depends only on s) + 2048 FMA
        float acc[32];
        #pragma unroll
        for (int a = 0; a < 32; ++a) acc[a] = 0.f;
        const float* Wb2 = lds + (size_t)(w * 32) * 256 + 4 * s;  // wave base + lane k offset
        #pragma unroll
        for (int t = 0; t < 16; ++t) {
            #pragma unroll
            for (int dl = 0; dl < 8; ++dl) {
                #pragma unroll
                for (int g = 0; g < 4; ++g) {
                    const float4 wv = *(const float4*)(Wb2 + ((dl * 4 + g) * 256 + 16 * t));
                    float a4 = acc[dl * 4 + g];
                    a4 = fmaf(wv.x, h4[t].x, a4);
                    a4 = fmaf(wv.y, h4[t].y, a4);
                    a4 = fmaf(wv.z, h4[t].z, a4);
                    a4 = fmaf(wv.w, h4[t].w, a4);
                    acc[dl * 4 + g] = a4;
                }
            }
        }

        // reduce over the 4 s-lanes (intra-quad DPP, no LDS)
        #pragma unroll
        for (int a = 0; a < 32; ++a) acc[a] += __shfl_xor(acc[a], 1);
        #pragma unroll
        for (int a = 0; a < 32; ++a) acc[a] += __shfl_xor(acc[a], 2);

        // extract this lane's dims (2s, 2s+1) — branchless, static indices
        float a0[4], a1[4];
        #pragma unroll
        for (int g = 0; g < 4; ++g) {
            a0[g] = mux4(s, acc[g],     acc[8 + g],  acc[16 + g], acc[24 + g]);
            a1[g] = mux4(s, acc[4 + g], acc[12 + g], acc[20 + g], acc[28 + g]);
        }

        // cell math (one row, two dims)
        const float ig0 = 1.f / (1.f + expf(-(a0[0] + pi0)));
        const float fg0 = 1.f / (1.f + expf(-(a0[1] + pf0)));
        const float og0 = 1.f / (1.f + expf(-(a0[3] + po0)));
        const float gt0 = tanhf(a0[2] + pg0);
        float cn0 = fg0 * c0 + ig0 * gt0;
        float hn0 = og0 * tanhf(cn0);
        const float ig1 = 1.f / (1.f + expf(-(a1[0] + pi1)));
        const float fg1 = 1.f / (1.f + expf(-(a1[1] + pf1)));
        const float og1 = 1.f / (1.f + expf(-(a1[3] + po1)));
        const float gt1 = tanhf(a1[2] + pg1);
        float cn1 = fg1 * c1 + ig1 * gt1;
        float hn1 = og1 * tanhf(cn1);
        if (dir) {                  // bwd rows inactive until p < len
            const bool v0 = (p < len);
            c0 = v0 ? cn0 : c0;  hn0 = v0 ? hn0 : 0.f;
            c1 = v0 ? cn1 : c1;  hn1 = v0 ? hn1 : 0.f;
        } else {
            c0 = cn0; c1 = cn1;
        }

        // publish h: two b32 LLC stores into [dim][row] layout (staging-compatible)
        {
            const size_t hxb = ((size_t)((gs & 1) * 2 + dir) * RG + i) * (HD * RPB);
            stg_llc_f(&hx[hxb + (size_t)dgo * RPB + r], hn0);
            stg_llc_f(&hx[hxb + (size_t)(dgo + 1) * RPB + r], hn1);
        }
        // H for emissions: [t][d][b] layout
        Hout[((size_t)p * HD + dgo) * BB + grow]     = hn0;
        Hout[((size_t)p * HD + dgo + 1) * BB + grow] = hn1;

        __syncthreads();   // vmcnt(0): h complete at LLC before flag
        if (tid == 0) stg_llc_i(&myflags[j], gs + 1);
    }

    float2 cout; cout.x = c0; cout.y = c1;
    *(float2*)&cbuf[((size_t)dir * BB + grow) * HD + dgo] = cout;
}

// ============================================================
// K3: emissions = [hf|hb] @ W_out^T + b_out -> emis[t][b][20]
// H layout [t][d][b].  (unchanged, proven)
// ============================================================
__global__ __launch_bounds__(256) void emis_kernel(
    const float* __restrict__ HF, const float* __restrict__ HB,
    const float* __restrict__ W_out, const float* __restrict__ b_out,
    float* __restrict__ emis)
{
    const int t = blockIdx.x;
    const int b = threadIdx.x & 63;
    int jg = threadIdx.x >> 6;
    jg = __builtin_amdgcn_readfirstlane(jg);

    float acc[5];
    #pragma unroll
    for (int u = 0; u < 5; ++u) acc[u] = b_out[jg + 4 * u];

    const float* hf = HF + (size_t)t * HD * BB + b;
    const float* hb = HB + (size_t)t * HD * BB + b;
    for (int k = 0; k < HD; ++k) {
        const float hv = hf[(size_t)k * BB];
        #pragma unroll
        for (int u = 0; u < 5; ++u)
            acc[u] = fmaf(hv, W_out[(size_t)(jg + 4 * u) * 512 + k], acc[u]);
    }
    for (int k = 0; k < HD; ++k) {
        const float hv = hb[(size_t)k * BB];
        #pragma unroll
        for (int u = 0; u < 5; ++u)
            acc[u] = fmaf(hv, W_out[(size_t)(jg + 4 * u) * 512 + HD + k], acc[u]);
    }
    #pragma unroll
    for (int u = 0; u < 5; ++u)
        emis[((size_t)t * BB + b) * KK + jg + 4 * u] = acc[u];
}

// ============================================================
// K4: Viterbi per batch row; exact first-max argmax; bp in LDS. (unchanged)
// ============================================================
__global__ __launch_bounds__(64) void viterbi_kernel(
    const float* __restrict__ emis, const int* __restrict__ lengths,
    const float* __restrict__ trans, const int* __restrict__ stop_id_p,
    float* __restrict__ out)
{
    __shared__ float tr[KK * KK];
    __shared__ float delta[KK], nd[KK];
    __shared__ unsigned char bp[TT][KK];
    const int b = blockIdx.x;
    const int tid = threadIdx.x;
    for (int i = tid; i < KK * KK; i += 64) tr[i] = trans[i];
    if (tid < KK) delta[tid] = 0.f;
    const int len = lengths[b];
    __syncthreads();

    for (int t = 0; t < TT; ++t) {
        if (tid < KK) {
            if (t < len) {
                float best = delta[0] + tr[tid * KK + 0];
                int am = 0;
                for (int p2 = 1; p2 < KK; ++p2) {
                    const float v = delta[p2] + tr[tid * KK + p2];
                    if (v > best) { best = v; am = p2; }
                }
                nd[tid] = best + emis[((size_t)t * BB + b) * KK + tid];
                bp[t][tid] = (unsigned char)am;
            } else {
                nd[tid] = delta[tid];
                bp[t][tid] = (unsigned char)tid;
            }
        }
        __syncthreads();
        if (tid < KK) delta[tid] = nd[tid];
        __syncthreads();
    }

    if (tid == 0) {
        const int stop_id = *stop_id_p;
        float best = delta[0] + tr[stop_id * KK + 0];
        int bl = 0;
        for (int jx = 1; jx < KK; ++jx) {
            const float v = delta[jx] + tr[stop_id * KK + jx];
            if (v > best) { best = v; bl = jx; }
        }
        out[b] = best;
        float* pout = out + BB + (size_t)b * (TT + 1);
        pout[TT] = (float)bl;
        int tag = bl;
        for (int t = TT - 1; t >= 0; --t) {
            tag = bp[t][tag];
            pout[t] = (float)tag;
        }
    }
}

// ============================================================
extern "C" void kernel_launch(void* const* d_in, const int* in_sizes, int n_in,
                              void* d_out, int out_size, void* d_ws, size_t ws_size,
                              hipStream_t stream) {
    const int*   sentence = (const int*)d_in[0];
    const int*   lengths  = (const int*)d_in[1];
    const int*   stop_id  = (const int*)d_in[3];
    const float* embed    = (const float*)d_in[4];
    const float* Wf_ih    = (const float*)d_in[5];
    const float* Wf_hh    = (const float*)d_in[6];
    const float* bf       = (const float*)d_in[7];
    const float* Wb_ih    = (const float*)d_in[8];
    const float* Wb_hh    = (const float*)d_in[9];
    const float* bb       = (const float*)d_in[10];
    const float* W_out    = (const float*)d_in[11];
    const float* b_out    = (const float*)d_in[12];
    const float* trans    = (const float*)d_in[13];
    float* out = (float*)d_out;

    const size_t hf_elems   = (size_t)TT * HD * BB;
    const size_t emis_elems = (size_t)TT * BB * KK;
    const size_t hx_elems   = (size_t)2 * 2 * RG * HD * RPB;  // 65536
    const size_t cbuf_elems = (size_t)2 * BB * HD;            // 32768
    const size_t flag_elems = (size_t)8 * 16;
    const size_t fixed_bytes = (2 * hf_elems + emis_elems + hx_elems + cbuf_elems + flag_elems) * 4;

    int CH = 0;
    const int cands[6] = {256, 128, 64, 32, 16, 8};
    for (int i = 0; i < 6; ++i) {
        const size_t need = fixed_bytes + 2ull * cands[i] * BB * NG * 4;
        if (need <= ws_size) { CH = cands[i]; break; }
    }
    if (CH == 0) return;

    float* Pf    = (float*)d_ws;
    float* Pb    = Pf + (size_t)CH * BB * NG;
    float* HF    = Pb + (size_t)CH * BB * NG;
    float* HB    = HF + hf_elems;
    float* emis  = HB + hf_elems;
    float* hx    = emis + emis_elems;
    float* cbuf  = hx + hx_elems;
    int*   flags = (int*)(cbuf + cbuf_elems);

    // allow >64KB dynamic LDS (idempotent host call; not a stream op)
    hipFuncSetAttribute((const void*)lstm_kernel,
                        hipFuncAttributeMaxDynamicSharedMemorySize,
                        LDS_FLOATS * 4);

    // zero hx (both parities), cbuf, flags — contiguous region
    hipMemsetAsync(hx, 0, (hx_elems + cbuf_elems + flag_elems) * 4, stream);

    const int nch = TT / CH;
    for (int c = 0; c < nch; ++c) {
        const int t0f = c * CH;
        const int t0b = TT - (c + 1) * CH;
        proj_kernel<<<dim3(CH, 32), 256, 0, stream>>>(
            sentence, embed, Wf_ih, bf, Wb_ih, bb, Pf, Pb, t0f, t0b);
        lstm_kernel<<<dim3(64), 256, LDS_FLOATS * 4, stream>>>(
            Pf, Pb, Wf_hh, Wb_hh, lengths, HF, HB, hx, cbuf, flags, c * CH, CH);
    }
    emis_kernel<<<dim3(TT), 256, 0, stream>>>(HF, HB, W_out, b_out, emis);
    viterbi_kernel<<<dim3(BB), 64, 0, stream>>>(emis, lengths, trans, stop_id, out);
}

// Round 5
// 4756.370 us; speedup vs baseline: 1.8959x; 1.8959x over previous
//
#include <hip/hip_runtime.h>
#include <math.h>

// Problem constants
#define TT 512
#define BB 64
#define EE 300
#define HD 256
#define KK 20
#define NG 1024        // gate rows per direction
#define RG 4           // row-groups per direction
#define RPB 16         // rows per block
#define DPG 16         // dims per block (16 dim-groups)
#define HS 260         // LDS h row stride (floats), padded
#define LDS_FLOATS (RPB * HS)   // 4160 floats = 16640 B (h slice only; W in VGPRs)

// Relaxed agent-scope atomics = cache-bypassing LLC ops (no fences anywhere;
// W/P stay cache-resident). Proven correct across prior rounds (absmax 0).
__device__ __forceinline__ int ldg_llc_i(const int* p) {
    return __hip_atomic_load(p, __ATOMIC_RELAXED, __HIP_MEMORY_SCOPE_AGENT);
}
__device__ __forceinline__ void stg_llc_i(int* p, int v) {
    __hip_atomic_store(p, v, __ATOMIC_RELAXED, __HIP_MEMORY_SCOPE_AGENT);
}
__device__ __forceinline__ unsigned long long ldg_llc_u64(const unsigned long long* p) {
    return __hip_atomic_load(p, __ATOMIC_RELAXED, __HIP_MEMORY_SCOPE_AGENT);
}
__device__ __forceinline__ void stg_llc_f(float* p, float v) {
    __hip_atomic_store(p, v, __ATOMIC_RELAXED, __HIP_MEMORY_SCOPE_AGENT);
}

// ============================================================
// K1: fused embedding-gather + input projection GEMM (fp32)
// P layout: [slot][row(64)][gate(1024)] (gate innermost).  (unchanged, proven)
// ============================================================
__global__ __launch_bounds__(256) void proj_kernel(
    const int* __restrict__ sentence, const float* __restrict__ embed,
    const float* __restrict__ Wf_ih, const float* __restrict__ bf,
    const float* __restrict__ Wb_ih, const float* __restrict__ bb,
    float* __restrict__ Pf, float* __restrict__ Pb, int t0f, int t0b)
{
    __shared__ float As[32][BB];
    __shared__ float Ws[32][64];
    const int s   = blockIdx.x;
    const int gb  = blockIdx.y;
    const int dir = gb >> 4;
    const int g0  = (gb & 15) * 64;
    const int tg  = dir ? (t0b + s) : (t0f + s);
    const int tid = threadIdx.x;
    const int tx = tid & 15, ty = tid >> 4;

    const int lrow = tid >> 2;
    const int kq   = tid & 3;
    const int word = sentence[lrow * TT + tg];
    const float* arow = embed + (size_t)word * EE;
    const float* Wih  = dir ? Wb_ih : Wf_ih;
    const float* bias = dir ? bb : bf;
    const float* wrow = Wih + (size_t)(g0 + lrow) * EE;

    float acc[4][4] = {};
    for (int k0 = 0; k0 < EE; k0 += 32) {
        __syncthreads();
        #pragma unroll
        for (int u = 0; u < 8; ++u) {
            const int k  = kq * 8 + u;
            const int kk = k0 + k;
            const bool ok = (kk < EE);
            As[k][lrow] = ok ? arow[kk] : 0.f;
            Ws[k][lrow] = ok ? wrow[kk] : 0.f;
        }
        __syncthreads();
        #pragma unroll
        for (int k = 0; k < 32; ++k) {
            const float4 a = *(const float4*)&As[k][ty * 4];
            const float4 w = *(const float4*)&Ws[k][tx * 4];
            acc[0][0] += a.x*w.x; acc[0][1] += a.x*w.y; acc[0][2] += a.x*w.z; acc[0][3] += a.x*w.w;
            acc[1][0] += a.y*w.x; acc[1][1] += a.y*w.y; acc[1][2] += a.y*w.z; acc[1][3] += a.y*w.w;
            acc[2][0] += a.z*w.x; acc[2][1] += a.z*w.y; acc[2][2] += a.z*w.z; acc[2][3] += a.z*w.w;
            acc[3][0] += a.w*w.x; acc[3][1] += a.w*w.y; acc[3][2] += a.w*w.z; acc[3][3] += a.w*w.w;
        }
    }
    float* Pd = (dir ? Pb : Pf) + (size_t)s * BB * NG;
    const float4 bv = *(const float4*)&bias[g0 + tx * 4];
    #pragma unroll
    for (int i = 0; i < 4; ++i) {
        float4 v;
        v.x = acc[i][0] + bv.x; v.y = acc[i][1] + bv.y;
        v.z = acc[i][2] + bv.z; v.w = acc[i][3] + bv.w;
        *(float4*)(Pd + (size_t)(ty * 4 + i) * NG + g0 + tx * 4) = v;
    }
}

// ============================================================
// K2: 2D-partitioned bidirectional LSTM, W_hh in REGISTERS (64/thread).
// 128 blocks x 256 threads. blk&7 = domain (dir*4 + row-group i, XCD residue);
// j = blk>>3 = dim-group 0..15 (16 dims each). Block owns 16 rows x 16 dims.
//
// Lane role: wave w -> dims j*16 + w*4 + d (d = lane>>4), s = lane&15 = k-slice
// {k = 4s + 64q, q=0..3} (16 k). W/thread = 4 gates x 4 float4 = 64 VGPR.
// Per step: poll 16 peer flags -> stage 16 KB h [r][k] (LLC->LDS, verbatim R0)
// -> GEMV: per row r: 4 ds_read_b128 of h (2-way conflicts only) x 16 FMA
//   -> acc[4][16] partials (this lane's 16-k slice, all rows)
// -> recursive-halving butterfly over the 16 s-lanes (60 shuffles, static
//   indices, live values halve each round) -> lane s owns row s's 4 gates
// -> cell math (1 row, 1 dim) -> publish h (LLC) -> flag.
// LDS wave-instrs/thread/step: 64 reads + 16 writes + 60 shuffles (~1/4 of R0)
// and 2x the CUs (128). Exchange protocol verbatim R0.
// ============================================================
__global__ __launch_bounds__(256, 1) void lstm_kernel(
    const float* __restrict__ Pf, const float* __restrict__ Pb,
    const float* __restrict__ Wf_hh, const float* __restrict__ Wb_hh,
    const int* __restrict__ lengths,
    float* __restrict__ HF, float* __restrict__ HB,
    float* __restrict__ hx,      // [parity][dir][rg][dim 256][row 16]
    float* __restrict__ cbuf,    // [dir][dim 256][row 64]
    int* __restrict__ flags,     // [dir*4+rg][16] (one 64B line per domain)
    int step0, int nsteps)
{
    __shared__ float lds[LDS_FLOATS];
    const int blk    = blockIdx.x;
    const int domain = blk & 7;          // dir*4 + i  (XCD residue)
    const int j      = blk >> 3;         // dim-group 0..15
    const int dir    = domain >> 2;
    const int i      = domain & 3;       // row-group
    const int tid    = threadIdx.x;
    const int w      = tid >> 6;         // wave 0..3
    const int lane   = tid & 63;
    const int d      = lane >> 4;        // dim-within-wave 0..3
    const int s      = lane & 15;        // k-slice / output row 0..15
    const int dg     = j * DPG + w * 4 + d;   // global dim 0..255
    const int grow   = i * RPB + s;           // this lane's output batch row

    const float* Whh = dir ? Wb_hh : Wf_hh;
    const float* P   = dir ? Pb : Pf;
    float* Hout = dir ? HB : HF;
    int* myflags = flags + domain * 16;
    const int len = lengths[grow];

    // ---- W_hh slice -> registers: wreg[g][q] = W[g*256+dg][4s + 64q .. +3]
    float4 wreg[4][4];
    #pragma unroll
    for (int g = 0; g < 4; ++g) {
        const float* wrow = Whh + (size_t)(g * HD + dg) * HD + 4 * s;
        #pragma unroll
        for (int q = 0; q < 4; ++q)
            wreg[g][q] = *(const float4*)(wrow + 64 * q);
    }

    // ---- cell state (this lane's single (dim,row))
    float c0 = cbuf[((size_t)dir * HD + dg) * BB + grow];

    for (int u = 0; u < nsteps; ++u) {
        const int gs   = step0 + u;
        const int p    = dir ? (TT - 1 - gs) : gs;
        const int slot = dir ? (nsteps - 1 - u) : u;

        // P terms (h-independent): 4 loads issued before the wait
        const float* Pp = P + (size_t)slot * BB * NG + (size_t)grow * NG + dg;
        const float pi0 = Pp[0], pf0 = Pp[256], pg0 = Pp[512], po0 = Pp[768];

        // wait: all 16 peers (dim-groups) of this domain finished step gs-1
        if (tid < 64) {
            const int* fl = myflags + (tid & 15);
            while (true) {
                const int v = ldg_llc_i(fl);
                if (__all(v >= gs)) break;
            }
        }
        __syncthreads();

        // stage h slice (16 KB) LLC -> LDS, transposing [k][r] -> [r][k]  (verbatim R0)
        {
            const unsigned long long* src = (const unsigned long long*)
                (hx + ((size_t)(((gs + 1) & 1) * 2 + dir) * RG + i) * (HD * RPB));
            const int kbase = tid >> 3, rp = tid & 7;
            #pragma unroll
            for (int it = 0; it < 8; ++it) {
                const int k = kbase + 32 * it;
                const unsigned long long v = ldg_llc_u64(&src[k * 8 + rp]);
                union { unsigned long long uu; float f[2]; } cv; cv.uu = v;
                lds[(2 * rp) * HS + k]     = cv.f[0];
                lds[(2 * rp + 1) * HS + k] = cv.f[1];
            }
        }
        __syncthreads();

        // GEMV partials: 4 gates x 16 rows over this lane's 16-k slice
        float acc[4][16];
        #pragma unroll
        for (int g = 0; g < 4; ++g)
            #pragma unroll
            for (int r = 0; r < 16; ++r) acc[g][r] = 0.f;

        #pragma unroll
        for (int r = 0; r < 16; ++r) {
            const float* hr = lds + r * HS + 4 * s;
            const float4 h0 = *(const float4*)(hr + 0);
            const float4 h1 = *(const float4*)(hr + 64);
            const float4 h2 = *(const float4*)(hr + 128);
            const float4 h3 = *(const float4*)(hr + 192);
            #pragma unroll
            for (int g = 0; g < 4; ++g) {
                float a4 = acc[g][r];
                a4 = fmaf(wreg[g][0].x, h0.x, a4); a4 = fmaf(wreg[g][0].y, h0.y, a4);
                a4 = fmaf(wreg[g][0].z, h0.z, a4); a4 = fmaf(wreg[g][0].w, h0.w, a4);
                a4 = fmaf(wreg[g][1].x, h1.x, a4); a4 = fmaf(wreg[g][1].y, h1.y, a4);
                a4 = fmaf(wreg[g][1].z, h1.z, a4); a4 = fmaf(wreg[g][1].w, h1.w, a4);
                a4 = fmaf(wreg[g][2].x, h2.x, a4); a4 = fmaf(wreg[g][2].y, h2.y, a4);
                a4 = fmaf(wreg[g][2].z, h2.z, a4); a4 = fmaf(wreg[g][2].w, h2.w, a4);
                a4 = fmaf(wreg[g][3].x, h3.x, a4); a4 = fmaf(wreg[g][3].y, h3.y, a4);
                a4 = fmaf(wreg[g][3].z, h3.z, a4); a4 = fmaf(wreg[g][3].w, h3.w, a4);
                acc[g][r] = a4;
            }
        }

        // recursive-halving butterfly over the 16 s-lanes: live values halve
        // each round; all indices compile-time static. End: lane s = row s.
        float r1[4][8];
        #pragma unroll
        for (int g = 0; g < 4; ++g)
            #pragma unroll
            for (int m = 0; m < 8; ++m) {
                const float sendv = (s & 1) ? acc[g][2*m]   : acc[g][2*m+1];
                const float keepv = (s & 1) ? acc[g][2*m+1] : acc[g][2*m];
                r1[g][m] = keepv + __shfl_xor(sendv, 1);
            }
        float r2[4][4];
        #pragma unroll
        for (int g = 0; g < 4; ++g)
            #pragma unroll
            for (int m = 0; m < 4; ++m) {
                const float sendv = (s & 2) ? r1[g][2*m]   : r1[g][2*m+1];
                const float keepv = (s & 2) ? r1[g][2*m+1] : r1[g][2*m];
                r2[g][m] = keepv + __shfl_xor(sendv, 2);
            }
        float r3[4][2];
        #pragma unroll
        for (int g = 0; g < 4; ++g)
            #pragma unroll
            for (int m = 0; m < 2; ++m) {
                const float sendv = (s & 4) ? r2[g][2*m]   : r2[g][2*m+1];
                const float keepv = (s & 4) ? r2[g][2*m+1] : r2[g][2*m];
                r3[g][m] = keepv + __shfl_xor(sendv, 4);
            }
        float res[4];
        #pragma unroll
        for (int g = 0; g < 4; ++g) {
            const float sendv = (s & 8) ? r3[g][0] : r3[g][1];
            const float keepv = (s & 8) ? r3[g][1] : r3[g][0];
            res[g] = keepv + __shfl_xor(sendv, 8);
        }

        // cell math (one row, one dim)
        const float ig0 = 1.f / (1.f + expf(-(res[0] + pi0)));
        const float fg0 = 1.f / (1.f + expf(-(res[1] + pf0)));
        const float og0 = 1.f / (1.f + expf(-(res[3] + po0)));
        const float gt0 = tanhf(res[2] + pg0);
        float cn0 = fg0 * c0 + ig0 * gt0;
        float hn0 = og0 * tanhf(cn0);
        if (dir) {                  // bwd rows inactive until p < len
            const bool v0 = (p < len);
            c0 = v0 ? cn0 : c0;  hn0 = v0 ? hn0 : 0.f;
        } else {
            c0 = cn0;
        }

        // publish h (1 KB/block): b32 LLC store into [dim][row] layout
        {
            const size_t hxb = ((size_t)((gs & 1) * 2 + dir) * RG + i) * (HD * RPB);
            stg_llc_f(&hx[hxb + (size_t)dg * RPB + s], hn0);
        }
        // H for emissions: [t][d][b] layout
        Hout[((size_t)p * HD + dg) * BB + grow] = hn0;

        __syncthreads();   // vmcnt(0): h complete at LLC before flag
        if (tid == 0) stg_llc_i(&myflags[j], gs + 1);
    }

    cbuf[((size_t)dir * HD + dg) * BB + grow] = c0;
}

// ============================================================
// K3: emissions = [hf|hb] @ W_out^T + b_out -> emis[t][b][20]
// H layout [t][d][b].  (unchanged, proven)
// ============================================================
__global__ __launch_bounds__(256) void emis_kernel(
    const float* __restrict__ HF, const float* __restrict__ HB,
    const float* __restrict__ W_out, const float* __restrict__ b_out,
    float* __restrict__ emis)
{
    const int t = blockIdx.x;
    const int b = threadIdx.x & 63;
    int jg = threadIdx.x >> 6;
    jg = __builtin_amdgcn_readfirstlane(jg);

    float acc[5];
    #pragma unroll
    for (int u = 0; u < 5; ++u) acc[u] = b_out[jg + 4 * u];

    const float* hf = HF + (size_t)t * HD * BB + b;
    const float* hb = HB + (size_t)t * HD * BB + b;
    for (int k = 0; k < HD; ++k) {
        const float hv = hf[(size_t)k * BB];
        #pragma unroll
        for (int u = 0; u < 5; ++u)
            acc[u] = fmaf(hv, W_out[(size_t)(jg + 4 * u) * 512 + k], acc[u]);
    }
    for (int k = 0; k < HD; ++k) {
        const float hv = hb[(size_t)k * BB];
        #pragma unroll
        for (int u = 0; u < 5; ++u)
            acc[u] = fmaf(hv, W_out[(size_t)(jg + 4 * u) * 512 + HD + k], acc[u]);
    }
    #pragma unroll
    for (int u = 0; u < 5; ++u)
        emis[((size_t)t * BB + b) * KK + jg + 4 * u] = acc[u];
}

// ============================================================
// K4: Viterbi per batch row; exact first-max argmax; bp in LDS. (unchanged)
// ============================================================
__global__ __launch_bounds__(64) void viterbi_kernel(
    const float* __restrict__ emis, const int* __restrict__ lengths,
    const float* __restrict__ trans, const int* __restrict__ stop_id_p,
    float* __restrict__ out)
{
    __shared__ float tr[KK * KK];
    __shared__ float delta[KK], nd[KK];
    __shared__ unsigned char bp[TT][KK];
    const int b = blockIdx.x;
    const int tid = threadIdx.x;
    for (int i = tid; i < KK * KK; i += 64) tr[i] = trans[i];
    if (tid < KK) delta[tid] = 0.f;
    const int len = lengths[b];
    __syncthreads();

    for (int t = 0; t < TT; ++t) {
        if (tid < KK) {
            if (t < len) {
                float best = delta[0] + tr[tid * KK + 0];
                int am = 0;
                for (int p2 = 1; p2 < KK; ++p2) {
                    const float v = delta[p2] + tr[tid * KK + p2];
                    if (v > best) { best = v; am = p2; }
                }
                nd[tid] = best + emis[((size_t)t * BB + b) * KK + tid];
                bp[t][tid] = (unsigned char)am;
            } else {
                nd[tid] = delta[tid];
                bp[t][tid] = (unsigned char)tid;
            }
        }
        __syncthreads();
        if (tid < KK) delta[tid] = nd[tid];
        __syncthreads();
    }

    if (tid == 0) {
        const int stop_id = *stop_id_p;
        float best = delta[0] + tr[stop_id * KK + 0];
        int bl = 0;
        for (int jx = 1; jx < KK; ++jx) {
            const float v = delta[jx] + tr[stop_id * KK + jx];
            if (v > best) { best = v; bl = jx; }
        }
        out[b] = best;
        float* pout = out + BB + (size_t)b * (TT + 1);
        pout[TT] = (float)bl;
        int tag = bl;
        for (int t = TT - 1; t >= 0; --t) {
            tag = bp[t][tag];
            pout[t] = (float)tag;
        }
    }
}

// ============================================================
extern "C" void kernel_launch(void* const* d_in, const int* in_sizes, int n_in,
                              void* d_out, int out_size, void* d_ws, size_t ws_size,
                              hipStream_t stream) {
    const int*   sentence = (const int*)d_in[0];
    const int*   lengths  = (const int*)d_in[1];
    const int*   stop_id  = (const int*)d_in[3];
    const float* embed    = (const float*)d_in[4];
    const float* Wf_ih    = (const float*)d_in[5];
    const float* Wf_hh    = (const float*)d_in[6];
    const float* bf       = (const float*)d_in[7];
    const float* Wb_ih    = (const float*)d_in[8];
    const float* Wb_hh    = (const float*)d_in[9];
    const float* bb       = (const float*)d_in[10];
    const float* W_out    = (const float*)d_in[11];
    const float* b_out    = (const float*)d_in[12];
    const float* trans    = (const float*)d_in[13];
    float* out = (float*)d_out;

    const size_t hf_elems   = (size_t)TT * HD * BB;
    const size_t emis_elems = (size_t)TT * BB * KK;
    const size_t hx_elems   = (size_t)2 * 2 * RG * HD * RPB;  // 65536
    const size_t cbuf_elems = (size_t)2 * HD * BB;            // 32768
    const size_t flag_elems = (size_t)8 * 16;
    const size_t fixed_bytes = (2 * hf_elems + emis_elems + hx_elems + cbuf_elems + flag_elems) * 4;

    int CH = 0;
    const int cands[6] = {256, 128, 64, 32, 16, 8};
    for (int i = 0; i < 6; ++i) {
        const size_t need = fixed_bytes + 2ull * cands[i] * BB * NG * 4;
        if (need <= ws_size) { CH = cands[i]; break; }
    }
    if (CH == 0) return;

    float* Pf    = (float*)d_ws;
    float* Pb    = Pf + (size_t)CH * BB * NG;
    float* HF    = Pb + (size_t)CH * BB * NG;
    float* HB    = HF + hf_elems;
    float* emis  = HB + hf_elems;
    float* hx    = emis + emis_elems;
    float* cbuf  = hx + hx_elems;
    int*   flags = (int*)(cbuf + cbuf_elems);

    // zero hx (both parities), cbuf, flags — contiguous region
    hipMemsetAsync(hx, 0, (hx_elems + cbuf_elems + flag_elems) * 4, stream);

    const int nch = TT / CH;
    for (int c = 0; c < nch; ++c) {
        const int t0f = c * CH;
        const int t0b = TT - (c + 1) * CH;
        proj_kernel<<<dim3(CH, 32), 256, 0, stream>>>(
            sentence, embed, Wf_ih, bf, Wb_ih, bb, Pf, Pb, t0f, t0b);
        lstm_kernel<<<dim3(128), 256, 0, stream>>>(
            Pf, Pb, Wf_hh, Wb_hh, lengths, HF, HB, hx, cbuf, flags, c * CH, CH);
    }
    emis_kernel<<<dim3(TT), 256, 0, stream>>>(HF, HB, W_out, b_out, emis);
    viterbi_kernel<<<dim3(BB), 64, 0, stream>>>(emis, lengths, trans, stop_id, out);
}

// Round 6
// 4705.605 us; speedup vs baseline: 1.9164x; 1.0108x over previous
//
#include <hip/hip_runtime.h>
#include <math.h>

// Problem constants
#define TT 512
#define BB 64
#define EE 300
#define HD 256
#define KK 20
#define NG 1024        // gate rows per direction
#define RGC 8          // row-groups (8 rows each)
#define RPBF 8         // rows per block
#define DPG 16         // dims per block (16 dim-groups)
#define HS 260         // LDS h row stride (floats), padded
#define LDSF (RPBF * HS)          // one direction's h buffer (2080 floats)
#define LDS_FLOATS (2 * LDSF)     // 4160 floats = 16640 B

// Relaxed agent-scope atomics = cache-bypassing LLC ops (no fences anywhere;
// W/P stay cache-resident). Proven correct across prior rounds (absmax 0).
__device__ __forceinline__ int ldg_llc_i(const int* p) {
    return __hip_atomic_load(p, __ATOMIC_RELAXED, __HIP_MEMORY_SCOPE_AGENT);
}
__device__ __forceinline__ void stg_llc_i(int* p, int v) {
    __hip_atomic_store(p, v, __ATOMIC_RELAXED, __HIP_MEMORY_SCOPE_AGENT);
}
__device__ __forceinline__ unsigned long long ldg_llc_u64(const unsigned long long* p) {
    return __hip_atomic_load(p, __ATOMIC_RELAXED, __HIP_MEMORY_SCOPE_AGENT);
}
__device__ __forceinline__ void stg_llc_f(float* p, float v) {
    __hip_atomic_store(p, v, __ATOMIC_RELAXED, __HIP_MEMORY_SCOPE_AGENT);
}

// ============================================================
// K1: fused embedding-gather + input projection GEMM (fp32)
// P layout: [slot][row(64)][gate(1024)] (gate innermost).  (unchanged, proven)
// ============================================================
__global__ __launch_bounds__(256) void proj_kernel(
    const int* __restrict__ sentence, const float* __restrict__ embed,
    const float* __restrict__ Wf_ih, const float* __restrict__ bf,
    const float* __restrict__ Wb_ih, const float* __restrict__ bb,
    float* __restrict__ Pf, float* __restrict__ Pb, int t0f, int t0b)
{
    __shared__ float As[32][BB];
    __shared__ float Ws[32][64];
    const int s   = blockIdx.x;
    const int gb  = blockIdx.y;
    const int dir = gb >> 4;
    const int g0  = (gb & 15) * 64;
    const int tg  = dir ? (t0b + s) : (t0f + s);
    const int tid = threadIdx.x;
    const int tx = tid & 15, ty = tid >> 4;

    const int lrow = tid >> 2;
    const int kq   = tid & 3;
    const int word = sentence[lrow * TT + tg];
    const float* arow = embed + (size_t)word * EE;
    const float* Wih  = dir ? Wb_ih : Wf_ih;
    const float* bias = dir ? bb : bf;
    const float* wrow = Wih + (size_t)(g0 + lrow) * EE;

    float acc[4][4] = {};
    for (int k0 = 0; k0 < EE; k0 += 32) {
        __syncthreads();
        #pragma unroll
        for (int u = 0; u < 8; ++u) {
            const int k  = kq * 8 + u;
            const int kk = k0 + k;
            const bool ok = (kk < EE);
            As[k][lrow] = ok ? arow[kk] : 0.f;
            Ws[k][lrow] = ok ? wrow[kk] : 0.f;
        }
        __syncthreads();
        #pragma unroll
        for (int k = 0; k < 32; ++k) {
            const float4 a = *(const float4*)&As[k][ty * 4];
            const float4 w = *(const float4*)&Ws[k][tx * 4];
            acc[0][0] += a.x*w.x; acc[0][1] += a.x*w.y; acc[0][2] += a.x*w.z; acc[0][3] += a.x*w.w;
            acc[1][0] += a.y*w.x; acc[1][1] += a.y*w.y; acc[1][2] += a.y*w.z; acc[1][3] += a.y*w.w;
            acc[2][0] += a.z*w.x; acc[2][1] += a.z*w.y; acc[2][2] += a.z*w.z; acc[2][3] += a.z*w.w;
            acc[3][0] += a.w*w.x; acc[3][1] += a.w*w.y; acc[3][2] += a.w*w.z; acc[3][3] += a.w*w.w;
        }
    }
    float* Pd = (dir ? Pb : Pf) + (size_t)s * BB * NG;
    const float4 bv = *(const float4*)&bias[g0 + tx * 4];
    #pragma unroll
    for (int i = 0; i < 4; ++i) {
        float4 v;
        v.x = acc[i][0] + bv.x; v.y = acc[i][1] + bv.y;
        v.z = acc[i][2] + bv.z; v.w = acc[i][3] + bv.w;
        *(float4*)(Pd + (size_t)(ty * 4 + i) * NG + g0 + tx * 4) = v;
    }
}

// GEMV core (R5-proven math at 8 rows): W in regs, h from LDS, partials over
// this lane's 16-k slice for 8 rows x 4 gates, then recursive-halving
// butterfly over the 16 s-lanes (static indices; values halve per round).
// End: lane s (and s+8, duplicated) holds row (s&7)'s 4 full gate sums.
__device__ __forceinline__ void gemv8(const float* __restrict__ base,
                                      const float4 (&wr)[4][4], int s,
                                      float res[4])
{
    float acc[4][8];
    #pragma unroll
    for (int g = 0; g < 4; ++g)
        #pragma unroll
        for (int r = 0; r < 8; ++r) acc[g][r] = 0.f;

    #pragma unroll
    for (int r = 0; r < 8; ++r) {
        const float* hr = base + r * HS + 4 * s;
        const float4 h0 = *(const float4*)(hr + 0);
        const float4 h1 = *(const float4*)(hr + 64);
        const float4 h2 = *(const float4*)(hr + 128);
        const float4 h3 = *(const float4*)(hr + 192);
        #pragma unroll
        for (int g = 0; g < 4; ++g) {
            float a4 = acc[g][r];
            a4 = fmaf(wr[g][0].x, h0.x, a4); a4 = fmaf(wr[g][0].y, h0.y, a4);
            a4 = fmaf(wr[g][0].z, h0.z, a4); a4 = fmaf(wr[g][0].w, h0.w, a4);
            a4 = fmaf(wr[g][1].x, h1.x, a4); a4 = fmaf(wr[g][1].y, h1.y, a4);
            a4 = fmaf(wr[g][1].z, h1.z, a4); a4 = fmaf(wr[g][1].w, h1.w, a4);
            a4 = fmaf(wr[g][2].x, h2.x, a4); a4 = fmaf(wr[g][2].y, h2.y, a4);
            a4 = fmaf(wr[g][2].z, h2.z, a4); a4 = fmaf(wr[g][2].w, h2.w, a4);
            a4 = fmaf(wr[g][3].x, h3.x, a4); a4 = fmaf(wr[g][3].y, h3.y, a4);
            a4 = fmaf(wr[g][3].z, h3.z, a4); a4 = fmaf(wr[g][3].w, h3.w, a4);
            acc[g][r] = a4;
        }
    }
    float r1[4][4];
    #pragma unroll
    for (int g = 0; g < 4; ++g)
        #pragma unroll
        for (int m = 0; m < 4; ++m) {
            const float sendv = (s & 1) ? acc[g][2*m]   : acc[g][2*m+1];
            const float keepv = (s & 1) ? acc[g][2*m+1] : acc[g][2*m];
            r1[g][m] = keepv + __shfl_xor(sendv, 1);
        }
    float r2[4][2];
    #pragma unroll
    for (int g = 0; g < 4; ++g)
        #pragma unroll
        for (int m = 0; m < 2; ++m) {
            const float sendv = (s & 2) ? r1[g][2*m]   : r1[g][2*m+1];
            const float keepv = (s & 2) ? r1[g][2*m+1] : r1[g][2*m];
            r2[g][m] = keepv + __shfl_xor(sendv, 2);
        }
    #pragma unroll
    for (int g = 0; g < 4; ++g) {
        const float sendv = (s & 4) ? r2[g][0] : r2[g][1];
        const float keepv = (s & 4) ? r2[g][1] : r2[g][0];
        const float r3 = keepv + __shfl_xor(sendv, 4);
        res[g] = r3 + __shfl_xor(r3, 8);
    }
}

// ============================================================
// K2: dual-direction LSTM, W_hh in regs (128/thread), pipelined exchange.
// 128 blocks x 256 threads. blk&7 = row-group rg (8 rows); j = blk>>3 =
// dim-group 0..15 (16 dims). Each block runs BOTH dirs for its tile.
// Lane: wave w -> dims j*16 + w*4 + (lane>>4); s = lane&15 = k-slice
// {4s+64q}. Lanes s and s+8 duplicate row (s&7) after the butterfly.
// Per step (R1's proven phase/flag schedule + R5's proven GEMV core):
//   A: [write fwd hregs->LDS_F | poll bwd flags>=gs] -> barrier ->
//      issue bwd h(gs-1) LLC loads -> GEMV fwd -> cell -> publish+flagF.
//   B: [write bwd hregs->LDS_B | poll fwd flags>=gs+1] -> barrier ->
//      issue fwd h(gs) LLC loads -> GEMV bwd -> cell -> publish+flagB.
// Each dir's poll-detect + 8KB stage latency hides under the OTHER dir's
// GEMV (the R5 counters showed ~2/3 of the step was this exposed latency).
// ============================================================
__global__ __launch_bounds__(256, 1) void lstm_kernel(
    const float* __restrict__ Pf, const float* __restrict__ Pb,
    const float* __restrict__ Wf_hh, const float* __restrict__ Wb_hh,
    const int* __restrict__ lengths,
    float* __restrict__ HF, float* __restrict__ HB,
    float* __restrict__ hx,      // [parity][dir][rg8][dim 256][row 8]
    float* __restrict__ cbuf,    // [dir][dim 256][row 64]
    int* __restrict__ flags,     // [dir*8+rg][16] (one 64B line per domain)
    int step0, int nsteps)
{
    __shared__ float lds[LDS_FLOATS];    // [0..LDSF) = fwd h, [LDSF..) = bwd h
    const int blk  = blockIdx.x;
    const int rg   = blk & 7;            // row-group (XCD residue)
    const int j    = blk >> 3;           // dim-group 0..15
    const int tid  = threadIdx.x;
    const int w    = tid >> 6;           // wave 0..3
    const int lane = tid & 63;
    const int d    = lane >> 4;          // dim-within-wave 0..3
    const int s    = lane & 15;          // k-slice 0..15
    const int rs   = s & 7;              // owned row 0..7 (dup at s, s+8)
    const int dg   = j * DPG + w * 4 + d;     // global dim 0..255
    const int grow = rg * RPBF + rs;          // global batch row

    int* flagF = flags + (0 * RGC + rg) * 16;
    int* flagB = flags + (RGC + rg) * 16;
    const int len = lengths[grow];

    // ---- W_hh slices (both dirs) -> registers: w[g][q] = W[g*256+dg][4s+64q..]
    float4 wF[4][4], wB[4][4];
    #pragma unroll
    for (int g = 0; g < 4; ++g) {
        const float* rowF = Wf_hh + (size_t)(g * HD + dg) * HD + 4 * s;
        const float* rowB = Wb_hh + (size_t)(g * HD + dg) * HD + 4 * s;
        #pragma unroll
        for (int q = 0; q < 4; ++q) {
            wF[g][q] = *(const float4*)(rowF + 64 * q);
            wB[g][q] = *(const float4*)(rowB + 64 * q);
        }
    }

    // ---- cell state
    float c_f = cbuf[((size_t)0 * HD + dg) * BB + grow];
    float c_b = cbuf[((size_t)1 * HD + dg) * BB + grow];

    const int kb = tid >> 2, rp = tid & 3;   // stage roles: dim base, row pair

    // ---- prologue: poll fwd flags >= step0, load fwd h(step0-1) -> regs
    if (tid < 64) {
        const int* fl = flagF + (tid & 15);
        int v; do { v = ldg_llc_i(fl); } while (!__all(v >= step0));
    }
    __syncthreads();
    unsigned long long hreg[4];
    {
        const unsigned long long* src = (const unsigned long long*)
            (hx + ((size_t)(((step0 + 1) & 1) * 2 + 0) * RGC + rg) * (HD * RPBF));
        #pragma unroll
        for (int it = 0; it < 4; ++it)
            hreg[it] = ldg_llc_u64(&src[(kb + 64 * it) * 4 + rp]);
    }

    for (int u = 0; u < nsteps; ++u) {
        const int gs  = step0 + u;
        const int pbt = TT - 1 - gs;     // original time index for bwd

        // P terms (h-independent), both dirs, issued early
        const float* PpF = Pf + ((size_t)u * BB + grow) * NG + dg;
        const float pfi = PpF[0], pff = PpF[256], pfg = PpF[512], pfo = PpF[768];
        const float* PpB = Pb + ((size_t)(nsteps - 1 - u) * BB + grow) * NG + dg;
        const float pbi = PpB[0], pbf = PpB[256], pbg = PpB[512], pbo = PpB[768];

        // ===== A phase: forward =====
        int fv = 0;
        if (tid < 64) fv = ldg_llc_i(flagB + (tid & 15));  // speculative
        #pragma unroll
        for (int it = 0; it < 4; ++it) {                   // fwd hregs -> LDS_F
            union { unsigned long long uu; float f[2]; } cv; cv.uu = hreg[it];
            const int k = kb + 64 * it;
            lds[(2 * rp) * HS + k]     = cv.f[0];
            lds[(2 * rp + 1) * HS + k] = cv.f[1];
        }
        if (tid < 64) {
            int v = fv;
            while (!__all(v >= gs)) v = ldg_llc_i(flagB + (tid & 15));
        }
        __syncthreads();
        // issue bwd h(gs-1) loads (parity (gs+1)&1) — fly under fwd GEMV
        {
            const unsigned long long* src = (const unsigned long long*)
                (hx + ((size_t)(((gs + 1) & 1) * 2 + 1) * RGC + rg) * (HD * RPBF));
            #pragma unroll
            for (int it = 0; it < 4; ++it)
                hreg[it] = ldg_llc_u64(&src[(kb + 64 * it) * 4 + rp]);
        }
        float res[4];
        gemv8(lds, wF, s, res);
        const float igf = 1.f / (1.f + expf(-(res[0] + pfi)));
        const float fgf = 1.f / (1.f + expf(-(res[1] + pff)));
        const float ogf = 1.f / (1.f + expf(-(res[3] + pfo)));
        const float gtf = tanhf(res[2] + pfg);
        c_f = fgf * c_f + igf * gtf;
        const float hnf = ogf * tanhf(c_f);
        if (s < 8)
            stg_llc_f(&hx[((size_t)((gs & 1) * 2 + 0) * RGC + rg) * (HD * RPBF)
                          + (size_t)dg * RPBF + rs], hnf);
        __syncthreads();   // vmcnt(0): h complete at LLC before flag
        if (tid == 0) stg_llc_i(&flagF[j], gs + 1);
        if (s < 8) HF[((size_t)gs * HD + dg) * BB + grow] = hnf;   // lazy

        // ===== B phase: backward =====
        int bv = 0;
        if (tid < 64) bv = ldg_llc_i(flagF + (tid & 15));  // speculative
        #pragma unroll
        for (int it = 0; it < 4; ++it) {                   // bwd hregs -> LDS_B
            union { unsigned long long uu; float f[2]; } cv; cv.uu = hreg[it];
            const int k = kb + 64 * it;
            lds[LDSF + (2 * rp) * HS + k]     = cv.f[0];
            lds[LDSF + (2 * rp + 1) * HS + k] = cv.f[1];
        }
        if (tid < 64) {
            int v = bv;
            while (!__all(v >= gs + 1)) v = ldg_llc_i(flagF + (tid & 15));
        }
        __syncthreads();
        // issue fwd h(gs) loads (parity gs&1) — fly under bwd GEMV
        {
            const unsigned long long* src = (const unsigned long long*)
                (hx + ((size_t)((gs & 1) * 2 + 0) * RGC + rg) * (HD * RPBF));
            #pragma unroll
            for (int it = 0; it < 4; ++it)
                hreg[it] = ldg_llc_u64(&src[(kb + 64 * it) * 4 + rp]);
        }
        gemv8(lds + LDSF, wB, s, res);
        const float igb = 1.f / (1.f + expf(-(res[0] + pbi)));
        const float fgb = 1.f / (1.f + expf(-(res[1] + pbf)));
        const float ogb = 1.f / (1.f + expf(-(res[3] + pbo)));
        const float gtb = tanhf(res[2] + pbg);
        const float cnb = fgb * c_b + igb * gtb;
        float hnb = ogb * tanhf(cnb);
        const bool vOK = (pbt < len);    // bwd rows inactive until p < len
        c_b = vOK ? cnb : c_b;
        hnb = vOK ? hnb : 0.f;
        if (s < 8)
            stg_llc_f(&hx[((size_t)((gs & 1) * 2 + 1) * RGC + rg) * (HD * RPBF)
                          + (size_t)dg * RPBF + rs], hnb);
        __syncthreads();   // vmcnt(0): h complete at LLC before flag
        if (tid == 0) stg_llc_i(&flagB[j], gs + 1);
        if (s < 8) HB[((size_t)pbt * HD + dg) * BB + grow] = hnb;  // lazy
    }

    if (s < 8) {
        cbuf[((size_t)0 * HD + dg) * BB + grow] = c_f;
        cbuf[((size_t)1 * HD + dg) * BB + grow] = c_b;
    }
}

// ============================================================
// K3: emissions = [hf|hb] @ W_out^T + b_out -> emis[t][b][20]
// H layout [t][d][b].  (unchanged, proven)
// ============================================================
__global__ __launch_bounds__(256) void emis_kernel(
    const float* __restrict__ HF, const float* __restrict__ HB,
    const float* __restrict__ W_out, const float* __restrict__ b_out,
    float* __restrict__ emis)
{
    const int t = blockIdx.x;
    const int b = threadIdx.x & 63;
    int jg = threadIdx.x >> 6;
    jg = __builtin_amdgcn_readfirstlane(jg);

    float acc[5];
    #pragma unroll
    for (int u = 0; u < 5; ++u) acc[u] = b_out[jg + 4 * u];

    const float* hf = HF + (size_t)t * HD * BB + b;
    const float* hb = HB + (size_t)t * HD * BB + b;
    for (int k = 0; k < HD; ++k) {
        const float hv = hf[(size_t)k * BB];
        #pragma unroll
        for (int u = 0; u < 5; ++u)
            acc[u] = fmaf(hv, W_out[(size_t)(jg + 4 * u) * 512 + k], acc[u]);
    }
    for (int k = 0; k < HD; ++k) {
        const float hv = hb[(size_t)k * BB];
        #pragma unroll
        for (int u = 0; u < 5; ++u)
            acc[u] = fmaf(hv, W_out[(size_t)(jg + 4 * u) * 512 + HD + k], acc[u]);
    }
    #pragma unroll
    for (int u = 0; u < 5; ++u)
        emis[((size_t)t * BB + b) * KK + jg + 4 * u] = acc[u];
}

// ============================================================
// K4: Viterbi per batch row; exact first-max argmax; bp in LDS. (unchanged)
// ============================================================
__global__ __launch_bounds__(64) void viterbi_kernel(
    const float* __restrict__ emis, const int* __restrict__ lengths,
    const float* __restrict__ trans, const int* __restrict__ stop_id_p,
    float* __restrict__ out)
{
    __shared__ float tr[KK * KK];
    __shared__ float delta[KK], nd[KK];
    __shared__ unsigned char bp[TT][KK];
    const int b = blockIdx.x;
    const int tid = threadIdx.x;
    for (int i = tid; i < KK * KK; i += 64) tr[i] = trans[i];
    if (tid < KK) delta[tid] = 0.f;
    const int len = lengths[b];
    __syncthreads();

    for (int t = 0; t < TT; ++t) {
        if (tid < KK) {
            if (t < len) {
                float best = delta[0] + tr[tid * KK + 0];
                int am = 0;
                for (int p2 = 1; p2 < KK; ++p2) {
                    const float v = delta[p2] + tr[tid * KK + p2];
                    if (v > best) { best = v; am = p2; }
                }
                nd[tid] = best + emis[((size_t)t * BB + b) * KK + tid];
                bp[t][tid] = (unsigned char)am;
            } else {
                nd[tid] = delta[tid];
                bp[t][tid] = (unsigned char)tid;
            }
        }
        __syncthreads();
        if (tid < KK) delta[tid] = nd[tid];
        __syncthreads();
    }

    if (tid == 0) {
        const int stop_id = *stop_id_p;
        float best = delta[0] + tr[stop_id * KK + 0];
        int bl = 0;
        for (int jx = 1; jx < KK; ++jx) {
            const float v = delta[jx] + tr[stop_id * KK + jx];
            if (v > best) { best = v; bl = jx; }
        }
        out[b] = best;
        float* pout = out + BB + (size_t)b * (TT + 1);
        pout[TT] = (float)bl;
        int tag = bl;
        for (int t = TT - 1; t >= 0; --t) {
            tag = bp[t][tag];
            pout[t] = (float)tag;
        }
    }
}

// ============================================================
extern "C" void kernel_launch(void* const* d_in, const int* in_sizes, int n_in,
                              void* d_out, int out_size, void* d_ws, size_t ws_size,
                              hipStream_t stream) {
    const int*   sentence = (const int*)d_in[0];
    const int*   lengths  = (const int*)d_in[1];
    const int*   stop_id  = (const int*)d_in[3];
    const float* embed    = (const float*)d_in[4];
    const float* Wf_ih    = (const float*)d_in[5];
    const float* Wf_hh    = (const float*)d_in[6];
    const float* bf       = (const float*)d_in[7];
    const float* Wb_ih    = (const float*)d_in[8];
    const float* Wb_hh    = (const float*)d_in[9];
    const float* bb       = (const float*)d_in[10];
    const float* W_out    = (const float*)d_in[11];
    const float* b_out    = (const float*)d_in[12];
    const float* trans    = (const float*)d_in[13];
    float* out = (float*)d_out;

    const size_t hf_elems   = (size_t)TT * HD * BB;
    const size_t emis_elems = (size_t)TT * BB * KK;
    const size_t hx_elems   = (size_t)2 * 2 * RGC * HD * RPBF; // 65536
    const size_t cbuf_elems = (size_t)2 * HD * BB;             // 32768
    const size_t flag_elems = (size_t)16 * 16;
    const size_t fixed_bytes = (2 * hf_elems + emis_elems + hx_elems + cbuf_elems + flag_elems) * 4;

    int CH = 0;
    const int cands[6] = {256, 128, 64, 32, 16, 8};
    for (int i = 0; i < 6; ++i) {
        const size_t need = fixed_bytes + 2ull * cands[i] * BB * NG * 4;
        if (need <= ws_size) { CH = cands[i]; break; }
    }
    if (CH == 0) return;

    float* Pf    = (float*)d_ws;
    float* Pb    = Pf + (size_t)CH * BB * NG;
    float* HF    = Pb + (size_t)CH * BB * NG;
    float* HB    = HF + hf_elems;
    float* emis  = HB + hf_elems;
    float* hx    = emis + emis_elems;
    float* cbuf  = hx + hx_elems;
    int*   flags = (int*)(cbuf + cbuf_elems);

    // zero hx (both parities), cbuf, flags — contiguous region
    hipMemsetAsync(hx, 0, (hx_elems + cbuf_elems + flag_elems) * 4, stream);

    const int nch = TT / CH;
    for (int c = 0; c < nch; ++c) {
        const int t0f = c * CH;
        const int t0b = TT - (c + 1) * CH;
        proj_kernel<<<dim3(CH, 32), 256, 0, stream>>>(
            sentence, embed, Wf_ih, bf, Wb_ih, bb, Pf, Pb, t0f, t0b);
        lstm_kernel<<<dim3(128), 256, 0, stream>>>(
            Pf, Pb, Wf_hh, Wb_hh, lengths, HF, HB, hx, cbuf, flags, c * CH, CH);
    }
    emis_kernel<<<dim3(TT), 256, 0, stream>>>(HF, HB, W_out, b_out, emis);
    viterbi_kernel<<<dim3(BB), 64, 0, stream>>>(emis, lengths, trans, stop_id, out);
}

// Round 7
// 4410.865 us; speedup vs baseline: 2.0444x; 1.0668x over previous
//
#include <hip/hip_runtime.h>
#include <math.h>

// Problem constants
#define TT 512
#define BB 64
#define EE 300
#define HD 256
#define KK 20
#define NG 1024        // gate rows per direction
#define RGC 8          // row-groups (8 rows each)
#define RPBF 8         // rows per block
#define DPG 16         // dims per block (16 dim-groups)
#define HS 260         // LDS h row stride (floats), padded
#define LDSF (RPBF * HS)          // one direction's h buffer (2080 floats)
#define LDS_FLOATS (2 * LDSF)     // 4160 floats = 16640 B
#define HXS 2048                  // u64 per (parity,dir,rg) slice: 256 dims x 8 rows

// Relaxed agent-scope atomics = cache-bypassing LLC ops (no fences anywhere;
// W/P stay cache-resident). Proven correct across prior rounds (absmax 0).
__device__ __forceinline__ unsigned long long ldg_llc_u64(const unsigned long long* p) {
    return __hip_atomic_load(p, __ATOMIC_RELAXED, __HIP_MEMORY_SCOPE_AGENT);
}
__device__ __forceinline__ void stg_llc_u64(unsigned long long* p, unsigned long long v) {
    __hip_atomic_store(p, v, __ATOMIC_RELAXED, __HIP_MEMORY_SCOPE_AGENT);
}
// pack h + step-tag into one self-validating word (tag = step+1; memset-0 == "h(-1) valid")
__device__ __forceinline__ unsigned long long pack_ht(float h, int tag) {
    return ((unsigned long long)(unsigned)tag << 32) | (unsigned long long)__float_as_uint(h);
}

// ============================================================
// K1: fused embedding-gather + input projection GEMM (fp32)
// P layout: [slot][row(64)][gate(1024)] (gate innermost).  (unchanged, proven)
// ============================================================
__global__ __launch_bounds__(256) void proj_kernel(
    const int* __restrict__ sentence, const float* __restrict__ embed,
    const float* __restrict__ Wf_ih, const float* __restrict__ bf,
    const float* __restrict__ Wb_ih, const float* __restrict__ bb,
    float* __restrict__ Pf, float* __restrict__ Pb, int t0f, int t0b)
{
    __shared__ float As[32][BB];
    __shared__ float Ws[32][64];
    const int s   = blockIdx.x;
    const int gb  = blockIdx.y;
    const int dir = gb >> 4;
    const int g0  = (gb & 15) * 64;
    const int tg  = dir ? (t0b + s) : (t0f + s);
    const int tid = threadIdx.x;
    const int tx = tid & 15, ty = tid >> 4;

    const int lrow = tid >> 2;
    const int kq   = tid & 3;
    const int word = sentence[lrow * TT + tg];
    const float* arow = embed + (size_t)word * EE;
    const float* Wih  = dir ? Wb_ih : Wf_ih;
    const float* bias = dir ? bb : bf;
    const float* wrow = Wih + (size_t)(g0 + lrow) * EE;

    float acc[4][4] = {};
    for (int k0 = 0; k0 < EE; k0 += 32) {
        __syncthreads();
        #pragma unroll
        for (int u = 0; u < 8; ++u) {
            const int k  = kq * 8 + u;
            const int kk = k0 + k;
            const bool ok = (kk < EE);
            As[k][lrow] = ok ? arow[kk] : 0.f;
            Ws[k][lrow] = ok ? wrow[kk] : 0.f;
        }
        __syncthreads();
        #pragma unroll
        for (int k = 0; k < 32; ++k) {
            const float4 a = *(const float4*)&As[k][ty * 4];
            const float4 w = *(const float4*)&Ws[k][tx * 4];
            acc[0][0] += a.x*w.x; acc[0][1] += a.x*w.y; acc[0][2] += a.x*w.z; acc[0][3] += a.x*w.w;
            acc[1][0] += a.y*w.x; acc[1][1] += a.y*w.y; acc[1][2] += a.y*w.z; acc[1][3] += a.y*w.w;
            acc[2][0] += a.z*w.x; acc[2][1] += a.z*w.y; acc[2][2] += a.z*w.z; acc[2][3] += a.z*w.w;
            acc[3][0] += a.w*w.x; acc[3][1] += a.w*w.y; acc[3][2] += a.w*w.z; acc[3][3] += a.w*w.w;
        }
    }
    float* Pd = (dir ? Pb : Pf) + (size_t)s * BB * NG;
    const float4 bv = *(const float4*)&bias[g0 + tx * 4];
    #pragma unroll
    for (int i = 0; i < 4; ++i) {
        float4 v;
        v.x = acc[i][0] + bv.x; v.y = acc[i][1] + bv.y;
        v.z = acc[i][2] + bv.z; v.w = acc[i][3] + bv.w;
        *(float4*)(Pd + (size_t)(ty * 4 + i) * NG + g0 + tx * 4) = v;
    }
}

// GEMV core (R5/R6-proven math): W slices, h from LDS, partials over this
// lane's 16-k slice for 8 rows x 4 gates, then recursive-halving butterfly
// over the 16 s-lanes (static indices; values halve per round).
// End: lane s (and s+8, duplicated) holds row (s&7)'s 4 full gate sums.
__device__ __forceinline__ void gemv8(const float* __restrict__ base,
                                      const float4 (&wr)[4][4], int s,
                                      float res[4])
{
    float acc[4][8];
    #pragma unroll
    for (int g = 0; g < 4; ++g)
        #pragma unroll
        for (int r = 0; r < 8; ++r) acc[g][r] = 0.f;

    #pragma unroll
    for (int r = 0; r < 8; ++r) {
        const float* hr = base + r * HS + 4 * s;
        const float4 h0 = *(const float4*)(hr + 0);
        const float4 h1 = *(const float4*)(hr + 64);
        const float4 h2 = *(const float4*)(hr + 128);
        const float4 h3 = *(const float4*)(hr + 192);
        #pragma unroll
        for (int g = 0; g < 4; ++g) {
            float a4 = acc[g][r];
            a4 = fmaf(wr[g][0].x, h0.x, a4); a4 = fmaf(wr[g][0].y, h0.y, a4);
            a4 = fmaf(wr[g][0].z, h0.z, a4); a4 = fmaf(wr[g][0].w, h0.w, a4);
            a4 = fmaf(wr[g][1].x, h1.x, a4); a4 = fmaf(wr[g][1].y, h1.y, a4);
            a4 = fmaf(wr[g][1].z, h1.z, a4); a4 = fmaf(wr[g][1].w, h1.w, a4);
            a4 = fmaf(wr[g][2].x, h2.x, a4); a4 = fmaf(wr[g][2].y, h2.y, a4);
            a4 = fmaf(wr[g][2].z, h2.z, a4); a4 = fmaf(wr[g][2].w, h2.w, a4);
            a4 = fmaf(wr[g][3].x, h3.x, a4); a4 = fmaf(wr[g][3].y, h3.y, a4);
            a4 = fmaf(wr[g][3].z, h3.z, a4); a4 = fmaf(wr[g][3].w, h3.w, a4);
            acc[g][r] = a4;
        }
    }
    float r1[4][4];
    #pragma unroll
    for (int g = 0; g < 4; ++g)
        #pragma unroll
        for (int m = 0; m < 4; ++m) {
            const float sendv = (s & 1) ? acc[g][2*m]   : acc[g][2*m+1];
            const float keepv = (s & 1) ? acc[g][2*m+1] : acc[g][2*m];
            r1[g][m] = keepv + __shfl_xor(sendv, 1);
        }
    float r2[4][2];
    #pragma unroll
    for (int g = 0; g < 4; ++g)
        #pragma unroll
        for (int m = 0; m < 2; ++m) {
            const float sendv = (s & 2) ? r1[g][2*m]   : r1[g][2*m+1];
            const float keepv = (s & 2) ? r1[g][2*m+1] : r1[g][2*m];
            r2[g][m] = keepv + __shfl_xor(sendv, 2);
        }
    #pragma unroll
    for (int g = 0; g < 4; ++g) {
        const float sendv = (s & 4) ? r2[g][0] : r2[g][1];
        const float keepv = (s & 4) ? r2[g][1] : r2[g][0];
        const float r3 = keepv + __shfl_xor(sendv, 4);
        res[g] = r3 + __shfl_xor(r3, 8);
    }
}

// ============================================================
// K2: dual-direction LSTM, SELF-VALIDATING (h,tag) EXCHANGE — no flags,
// no store-drain, no poll phase. 128 blocks x 256 threads.
// blk&7 = row-group rg (8 rows); j = blk>>3 = dim-group (16 dims).
// hx2[parity][dir][rg][dim 256][row 8] of u64 = (float h, int tag=step+1);
// memset-0 == valid initial state h(-1) (tag 0 == step0=0's expectation).
//
// Per phase: stage verified hregs -> LDS -> barrier -> issue next u64 loads
// -> GEMV -> verify tags (reload if stale; normally 0 retries: producer ran
// a phase earlier and visibility hides under GEMV) -> cell -> publish (h,tag)
// u64 stores, fire-and-forget. Exactly ONE barrier per phase.
// Overwrite safety is transitive: publishing tag t+2 into a slot requires a
// verified read of all peers' tag t+1, which each peer publishes only after
// its own verified read of tag t from that slot.
// ============================================================
__global__ __launch_bounds__(256, 1) void lstm_kernel(
    const float* __restrict__ Pf, const float* __restrict__ Pb,
    const float* __restrict__ Wf_hh, const float* __restrict__ Wb_hh,
    const int* __restrict__ lengths,
    float* __restrict__ HF, float* __restrict__ HB,
    unsigned long long* __restrict__ hx2,  // [parity][dir][rg8][dim 256][row 8] u64
    float* __restrict__ cbuf,              // [dir][dim 256][row 64]
    int step0, int nsteps)
{
    __shared__ float lds[LDS_FLOATS];    // [0..LDSF) = fwd h, [LDSF..) = bwd h
    const int blk  = blockIdx.x;
    const int rg   = blk & 7;            // row-group (XCD residue)
    const int j    = blk >> 3;           // dim-group 0..15
    const int tid  = threadIdx.x;
    const int w    = tid >> 6;           // wave 0..3
    const int lane = tid & 63;
    const int d    = lane >> 4;          // dim-within-wave 0..3
    const int s    = lane & 15;          // k-slice 0..15
    const int rs   = s & 7;              // owned row 0..7 (dup at s, s+8)
    const int dg   = j * DPG + w * 4 + d;     // global dim 0..255
    const int grow = rg * RPBF + rs;          // global batch row
    const int kk   = tid >> 3, rr = tid & 7;  // stage-load roles

    const int len = lengths[grow];

    // ---- W_hh slices (both dirs): w[g][q] = W[g*256+dg][4s+64q..]
    float4 wF[4][4], wB[4][4];
    #pragma unroll
    for (int g = 0; g < 4; ++g) {
        const float* rowF = Wf_hh + (size_t)(g * HD + dg) * HD + 4 * s;
        const float* rowB = Wb_hh + (size_t)(g * HD + dg) * HD + 4 * s;
        #pragma unroll
        for (int q = 0; q < 4; ++q) {
            wF[g][q] = *(const float4*)(rowF + 64 * q);
            wB[g][q] = *(const float4*)(rowB + 64 * q);
        }
    }

    // ---- cell state
    float c_f = cbuf[((size_t)0 * HD + dg) * BB + grow];
    float c_b = cbuf[((size_t)1 * HD + dg) * BB + grow];

    // ---- prologue: load + verify fwd h(step0-1) (tag step0, parity (step0+1)&1)
    unsigned long long hreg[8];
    {
        const unsigned long long* src = hx2 +
            ((size_t)(((step0 + 1) & 1) * 2 + 0) * RGC + rg) * HXS;
        #pragma unroll
        for (int it = 0; it < 8; ++it) {
            const unsigned long long* a = &src[(kk + 32 * it) * 8 + rr];
            unsigned long long v = ldg_llc_u64(a);
            while ((int)(v >> 32) != step0) v = ldg_llc_u64(a);
            hreg[it] = v;
        }
    }

    for (int u = 0; u < nsteps; ++u) {
        const int gs  = step0 + u;
        const int pbt = TT - 1 - gs;     // original time index for bwd

        // P terms (h-independent), both dirs, issued early
        const float* PpF = Pf + ((size_t)u * BB + grow) * NG + dg;
        const float pfi = PpF[0], pff = PpF[256], pfg = PpF[512], pfo = PpF[768];
        const float* PpB = Pb + ((size_t)(nsteps - 1 - u) * BB + grow) * NG + dg;
        const float pbi = PpB[0], pbf = PpB[256], pbg = PpB[512], pbo = PpB[768];

        // ===== A phase: forward =====
        #pragma unroll
        for (int it = 0; it < 8; ++it)      // verified fwd h(gs-1) -> LDS_F
            lds[rr * HS + kk + 32 * it] =
                __uint_as_float((unsigned)(hreg[it] & 0xffffffffull));
        __syncthreads();
        // issue bwd h(gs-1) loads (tag gs, parity (gs+1)&1) — verify after GEMV
        const unsigned long long* srcB = hx2 +
            ((size_t)(((gs + 1) & 1) * 2 + 1) * RGC + rg) * HXS;
        #pragma unroll
        for (int it = 0; it < 8; ++it)
            hreg[it] = ldg_llc_u64(&srcB[(kk + 32 * it) * 8 + rr]);

        float res[4];
        gemv8(lds, wF, s, res);

        #pragma unroll
        for (int it = 0; it < 8; ++it) {    // verify bwd tags == gs
            unsigned long long v = hreg[it];
            if ((int)(v >> 32) != gs) {
                const unsigned long long* a = &srcB[(kk + 32 * it) * 8 + rr];
                do { v = ldg_llc_u64(a); } while ((int)(v >> 32) != gs);
            }
            hreg[it] = v;
        }

        const float igf = 1.f / (1.f + expf(-(res[0] + pfi)));
        const float fgf = 1.f / (1.f + expf(-(res[1] + pff)));
        const float ogf = 1.f / (1.f + expf(-(res[3] + pfo)));
        const float gtf = tanhf(res[2] + pfg);
        c_f = fgf * c_f + igf * gtf;
        const float hnf = ogf * tanhf(c_f);
        if (s < 8) {
            stg_llc_u64(&hx2[((size_t)((gs & 1) * 2 + 0) * RGC + rg) * HXS
                             + (size_t)dg * 8 + rs], pack_ht(hnf, gs + 1));
            HF[((size_t)gs * HD + dg) * BB + grow] = hnf;
        }

        // ===== B phase: backward =====
        #pragma unroll
        for (int it = 0; it < 8; ++it)      // verified bwd h(gs-1) -> LDS_B
            lds[LDSF + rr * HS + kk + 32 * it] =
                __uint_as_float((unsigned)(hreg[it] & 0xffffffffull));
        __syncthreads();
        // issue fwd h(gs) loads (tag gs+1, parity gs&1) — verify after GEMV
        const unsigned long long* srcF = hx2 +
            ((size_t)((gs & 1) * 2 + 0) * RGC + rg) * HXS;
        #pragma unroll
        for (int it = 0; it < 8; ++it)
            hreg[it] = ldg_llc_u64(&srcF[(kk + 32 * it) * 8 + rr]);

        gemv8(lds + LDSF, wB, s, res);

        #pragma unroll
        for (int it = 0; it < 8; ++it) {    // verify fwd tags == gs+1
            unsigned long long v = hreg[it];
            if ((int)(v >> 32) != gs + 1) {
                const unsigned long long* a = &srcF[(kk + 32 * it) * 8 + rr];
                do { v = ldg_llc_u64(a); } while ((int)(v >> 32) != gs + 1);
            }
            hreg[it] = v;
        }

        const float igb = 1.f / (1.f + expf(-(res[0] + pbi)));
        const float fgb = 1.f / (1.f + expf(-(res[1] + pbf)));
        const float ogb = 1.f / (1.f + expf(-(res[3] + pbo)));
        const float gtb = tanhf(res[2] + pbg);
        const float cnb = fgb * c_b + igb * gtb;
        float hnb = ogb * tanhf(cnb);
        const bool vOK = (pbt < len);    // bwd rows inactive until p < len
        c_b = vOK ? cnb : c_b;
        hnb = vOK ? hnb : 0.f;
        if (s < 8) {
            stg_llc_u64(&hx2[((size_t)((gs & 1) * 2 + 1) * RGC + rg) * HXS
                             + (size_t)dg * 8 + rs], pack_ht(hnb, gs + 1));
            HB[((size_t)pbt * HD + dg) * BB + grow] = hnb;
        }
    }

    if (s < 8) {
        cbuf[((size_t)0 * HD + dg) * BB + grow] = c_f;
        cbuf[((size_t)1 * HD + dg) * BB + grow] = c_b;
    }
}

// ============================================================
// K3: emissions = [hf|hb] @ W_out^T + b_out -> emis[t][b][20]
// H layout [t][d][b].  (unchanged, proven)
// ============================================================
__global__ __launch_bounds__(256) void emis_kernel(
    const float* __restrict__ HF, const float* __restrict__ HB,
    const float* __restrict__ W_out, const float* __restrict__ b_out,
    float* __restrict__ emis)
{
    const int t = blockIdx.x;
    const int b = threadIdx.x & 63;
    int jg = threadIdx.x >> 6;
    jg = __builtin_amdgcn_readfirstlane(jg);

    float acc[5];
    #pragma unroll
    for (int u = 0; u < 5; ++u) acc[u] = b_out[jg + 4 * u];

    const float* hf = HF + (size_t)t * HD * BB + b;
    const float* hb = HB + (size_t)t * HD * BB + b;
    for (int k = 0; k < HD; ++k) {
        const float hv = hf[(size_t)k * BB];
        #pragma unroll
        for (int u = 0; u < 5; ++u)
            acc[u] = fmaf(hv, W_out[(size_t)(jg + 4 * u) * 512 + k], acc[u]);
    }
    for (int k = 0; k < HD; ++k) {
        const float hv = hb[(size_t)k * BB];
        #pragma unroll
        for (int u = 0; u < 5; ++u)
            acc[u] = fmaf(hv, W_out[(size_t)(jg + 4 * u) * 512 + HD + k], acc[u]);
    }
    #pragma unroll
    for (int u = 0; u < 5; ++u)
        emis[((size_t)t * BB + b) * KK + jg + 4 * u] = acc[u];
}

// ============================================================
// K4: Viterbi per batch row; exact first-max argmax; bp in LDS. (unchanged)
// ============================================================
__global__ __launch_bounds__(64) void viterbi_kernel(
    const float* __restrict__ emis, const int* __restrict__ lengths,
    const float* __restrict__ trans, const int* __restrict__ stop_id_p,
    float* __restrict__ out)
{
    __shared__ float tr[KK * KK];
    __shared__ float delta[KK], nd[KK];
    __shared__ unsigned char bp[TT][KK];
    const int b = blockIdx.x;
    const int tid = threadIdx.x;
    for (int i = tid; i < KK * KK; i += 64) tr[i] = trans[i];
    if (tid < KK) delta[tid] = 0.f;
    const int len = lengths[b];
    __syncthreads();

    for (int t = 0; t < TT; ++t) {
        if (tid < KK) {
            if (t < len) {
                float best = delta[0] + tr[tid * KK + 0];
                int am = 0;
                for (int p2 = 1; p2 < KK; ++p2) {
                    const float v = delta[p2] + tr[tid * KK + p2];
                    if (v > best) { best = v; am = p2; }
                }
                nd[tid] = best + emis[((size_t)t * BB + b) * KK + tid];
                bp[t][tid] = (unsigned char)am;
            } else {
                nd[tid] = delta[tid];
                bp[t][tid] = (unsigned char)tid;
            }
        }
        __syncthreads();
        if (tid < KK) delta[tid] = nd[tid];
        __syncthreads();
    }

    if (tid == 0) {
        const int stop_id = *stop_id_p;
        float best = delta[0] + tr[stop_id * KK + 0];
        int bl = 0;
        for (int jx = 1; jx < KK; ++jx) {
            const float v = delta[jx] + tr[stop_id * KK + jx];
            if (v > best) { best = v; bl = jx; }
        }
        out[b] = best;
        float* pout = out + BB + (size_t)b * (TT + 1);
        pout[TT] = (float)bl;
        int tag = bl;
        for (int t = TT - 1; t >= 0; --t) {
            tag = bp[t][tag];
            pout[t] = (float)tag;
        }
    }
}

// ============================================================
extern "C" void kernel_launch(void* const* d_in, const int* in_sizes, int n_in,
                              void* d_out, int out_size, void* d_ws, size_t ws_size,
                              hipStream_t stream) {
    const int*   sentence = (const int*)d_in[0];
    const int*   lengths  = (const int*)d_in[1];
    const int*   stop_id  = (const int*)d_in[3];
    const float* embed    = (const float*)d_in[4];
    const float* Wf_ih    = (const float*)d_in[5];
    const float* Wf_hh    = (const float*)d_in[6];
    const float* bf       = (const float*)d_in[7];
    const float* Wb_ih    = (const float*)d_in[8];
    const float* Wb_hh    = (const float*)d_in[9];
    const float* bb       = (const float*)d_in[10];
    const float* W_out    = (const float*)d_in[11];
    const float* b_out    = (const float*)d_in[12];
    const float* trans    = (const float*)d_in[13];
    float* out = (float*)d_out;

    const size_t hf_elems   = (size_t)TT * HD * BB;
    const size_t emis_elems = (size_t)TT * BB * KK;
    const size_t hx_u64     = (size_t)2 * 2 * RGC * HD * RPBF; // 65536 u64
    const size_t cbuf_elems = (size_t)2 * HD * BB;             // 32768
    const size_t fixed_bytes = (2 * hf_elems + emis_elems + cbuf_elems) * 4 + hx_u64 * 8;

    int CH = 0;
    const int cands[6] = {256, 128, 64, 32, 16, 8};
    for (int i = 0; i < 6; ++i) {
        const size_t need = fixed_bytes + 2ull * cands[i] * BB * NG * 4;
        if (need <= ws_size) { CH = cands[i]; break; }
    }
    if (CH == 0) return;

    float* Pf    = (float*)d_ws;
    float* Pb    = Pf + (size_t)CH * BB * NG;
    float* HF    = Pb + (size_t)CH * BB * NG;
    float* HB    = HF + hf_elems;
    float* emis  = HB + hf_elems;
    unsigned long long* hx2 = (unsigned long long*)(emis + emis_elems); // 8B-aligned (even float offset)
    float* cbuf  = (float*)(hx2 + hx_u64);

    // zero hx2 (tags 0 == valid initial h(-1)) + cbuf — contiguous region
    hipMemsetAsync(hx2, 0, hx_u64 * 8 + cbuf_elems * 4, stream);

    const int nch = TT / CH;
    for (int c = 0; c < nch; ++c) {
        const int t0f = c * CH;
        const int t0b = TT - (c + 1) * CH;
        proj_kernel<<<dim3(CH, 32), 256, 0, stream>>>(
            sentence, embed, Wf_ih, bf, Wb_ih, bb, Pf, Pb, t0f, t0b);
        lstm_kernel<<<dim3(128), 256, 0, stream>>>(
            Pf, Pb, Wf_hh, Wb_hh, lengths, HF, HB, hx2, cbuf, c * CH, CH);
    }
    emis_kernel<<<dim3(TT), 256, 0, stream>>>(HF, HB, W_out, b_out, emis);
    viterbi_kernel<<<dim3(BB), 64, 0, stream>>>(emis, lengths, trans, stop_id, out);
}

// Round 8
// 3858.462 us; speedup vs baseline: 2.3371x; 1.1432x over previous
//
#include <hip/hip_runtime.h>
#include <math.h>

// Problem constants
#define TT 512
#define BB 64
#define EE 300
#define HD 256
#define KK 20
#define NG 1024        // gate rows per direction
#define RGC 8          // row-groups (8 rows each)
#define RPBF 8         // rows per block
#define HS 260         // LDS h row stride (floats), padded
#define LDSF (RPBF * HS)          // one direction's h buffer (2080 floats)
#define LDS_FLOATS (2 * LDSF)     // 4160 floats = 16640 B
#define HXS 2048                  // u64 per (parity,dir,rg) slice: 256 dims x 8 rows

// Relaxed agent-scope atomics = cache-bypassing LLC ops (no fences anywhere;
// W/P stay cache-resident). Proven correct across prior rounds (absmax 0).
__device__ __forceinline__ unsigned long long ldg_llc_u64(const unsigned long long* p) {
    return __hip_atomic_load(p, __ATOMIC_RELAXED, __HIP_MEMORY_SCOPE_AGENT);
}
__device__ __forceinline__ void stg_llc_u64(unsigned long long* p, unsigned long long v) {
    __hip_atomic_store(p, v, __ATOMIC_RELAXED, __HIP_MEMORY_SCOPE_AGENT);
}
// pack h + step-tag into one self-validating word (tag = step+1; memset-0 == "h(-1) valid")
__device__ __forceinline__ unsigned long long pack_ht(float h, int tag) {
    return ((unsigned long long)(unsigned)tag << 32) | (unsigned long long)__float_as_uint(h);
}

// ============================================================
// K1: fused embedding-gather + input projection GEMM (fp32)
// P layout: [slot][row(64)][gate(1024)] (gate innermost).  (unchanged, proven)
// ============================================================
__global__ __launch_bounds__(256) void proj_kernel(
    const int* __restrict__ sentence, const float* __restrict__ embed,
    const float* __restrict__ Wf_ih, const float* __restrict__ bf,
    const float* __restrict__ Wb_ih, const float* __restrict__ bb,
    float* __restrict__ Pf, float* __restrict__ Pb, int t0f, int t0b)
{
    __shared__ float As[32][BB];
    __shared__ float Ws[32][64];
    const int s   = blockIdx.x;
    const int gb  = blockIdx.y;
    const int dir = gb >> 4;
    const int g0  = (gb & 15) * 64;
    const int tg  = dir ? (t0b + s) : (t0f + s);
    const int tid = threadIdx.x;
    const int tx = tid & 15, ty = tid >> 4;

    const int lrow = tid >> 2;
    const int kq   = tid & 3;
    const int word = sentence[lrow * TT + tg];
    const float* arow = embed + (size_t)word * EE;
    const float* Wih  = dir ? Wb_ih : Wf_ih;
    const float* bias = dir ? bb : bf;
    const float* wrow = Wih + (size_t)(g0 + lrow) * EE;

    float acc[4][4] = {};
    for (int k0 = 0; k0 < EE; k0 += 32) {
        __syncthreads();
        #pragma unroll
        for (int u = 0; u < 8; ++u) {
            const int k  = kq * 8 + u;
            const int kk = k0 + k;
            const bool ok = (kk < EE);
            As[k][lrow] = ok ? arow[kk] : 0.f;
            Ws[k][lrow] = ok ? wrow[kk] : 0.f;
        }
        __syncthreads();
        #pragma unroll
        for (int k = 0; k < 32; ++k) {
            const float4 a = *(const float4*)&As[k][ty * 4];
            const float4 w = *(const float4*)&Ws[k][tx * 4];
            acc[0][0] += a.x*w.x; acc[0][1] += a.x*w.y; acc[0][2] += a.x*w.z; acc[0][3] += a.x*w.w;
            acc[1][0] += a.y*w.x; acc[1][1] += a.y*w.y; acc[1][2] += a.y*w.z; acc[1][3] += a.y*w.w;
            acc[2][0] += a.z*w.x; acc[2][1] += a.z*w.y; acc[2][2] += a.z*w.z; acc[2][3] += a.z*w.w;
            acc[3][0] += a.w*w.x; acc[3][1] += a.w*w.y; acc[3][2] += a.w*w.z; acc[3][3] += a.w*w.w;
        }
    }
    float* Pd = (dir ? Pb : Pf) + (size_t)s * BB * NG;
    const float4 bv = *(const float4*)&bias[g0 + tx * 4];
    #pragma unroll
    for (int i = 0; i < 4; ++i) {
        float4 v;
        v.x = acc[i][0] + bv.x; v.y = acc[i][1] + bv.y;
        v.z = acc[i][2] + bv.z; v.w = acc[i][3] + bv.w;
        *(float4*)(Pd + (size_t)(ty * 4 + i) * NG + g0 + tx * 4) = v;
    }
}

// GEMV core (R5/R6/R7-proven math): W in regs, h from LDS, partials over this
// lane's 16-k slice for 8 rows x 4 gates, then recursive-halving butterfly
// over the 16 s-lanes (static indices; values halve per round).
// End: lane s (and s+8, duplicated) holds row (s&7)'s 4 full gate sums.
__device__ __forceinline__ void gemv8(const float* __restrict__ base,
                                      const float4 (&wr)[4][4], int s,
                                      float res[4])
{
    float acc[4][8];
    #pragma unroll
    for (int g = 0; g < 4; ++g)
        #pragma unroll
        for (int r = 0; r < 8; ++r) acc[g][r] = 0.f;

    #pragma unroll
    for (int r = 0; r < 8; ++r) {
        const float* hr = base + r * HS + 4 * s;
        const float4 h0 = *(const float4*)(hr + 0);
        const float4 h1 = *(const float4*)(hr + 64);
        const float4 h2 = *(const float4*)(hr + 128);
        const float4 h3 = *(const float4*)(hr + 192);
        #pragma unroll
        for (int g = 0; g < 4; ++g) {
            float a4 = acc[g][r];
            a4 = fmaf(wr[g][0].x, h0.x, a4); a4 = fmaf(wr[g][0].y, h0.y, a4);
            a4 = fmaf(wr[g][0].z, h0.z, a4); a4 = fmaf(wr[g][0].w, h0.w, a4);
            a4 = fmaf(wr[g][1].x, h1.x, a4); a4 = fmaf(wr[g][1].y, h1.y, a4);
            a4 = fmaf(wr[g][1].z, h1.z, a4); a4 = fmaf(wr[g][1].w, h1.w, a4);
            a4 = fmaf(wr[g][2].x, h2.x, a4); a4 = fmaf(wr[g][2].y, h2.y, a4);
            a4 = fmaf(wr[g][2].z, h2.z, a4); a4 = fmaf(wr[g][2].w, h2.w, a4);
            a4 = fmaf(wr[g][3].x, h3.x, a4); a4 = fmaf(wr[g][3].y, h3.y, a4);
            a4 = fmaf(wr[g][3].z, h3.z, a4); a4 = fmaf(wr[g][3].w, h3.w, a4);
            acc[g][r] = a4;
        }
    }
    float r1[4][4];
    #pragma unroll
    for (int g = 0; g < 4; ++g)
        #pragma unroll
        for (int m = 0; m < 4; ++m) {
            const float sendv = (s & 1) ? acc[g][2*m]   : acc[g][2*m+1];
            const float keepv = (s & 1) ? acc[g][2*m+1] : acc[g][2*m];
            r1[g][m] = keepv + __shfl_xor(sendv, 1);
        }
    float r2[4][2];
    #pragma unroll
    for (int g = 0; g < 4; ++g)
        #pragma unroll
        for (int m = 0; m < 2; ++m) {
            const float sendv = (s & 2) ? r1[g][2*m]   : r1[g][2*m+1];
            const float keepv = (s & 2) ? r1[g][2*m+1] : r1[g][2*m];
            r2[g][m] = keepv + __shfl_xor(sendv, 2);
        }
    #pragma unroll
    for (int g = 0; g < 4; ++g) {
        const float sendv = (s & 4) ? r2[g][0] : r2[g][1];
        const float keepv = (s & 4) ? r2[g][1] : r2[g][0];
        const float r3 = keepv + __shfl_xor(sendv, 4);
        res[g] = r3 + __shfl_xor(r3, 8);
    }
}

// ============================================================
// K2: WAVE-SPECIALIZED dual-direction LSTM, merged single-phase step.
// 256 blocks x 256 threads (1 block/CU, all co-resident).
// blk&7 = row-group rg (8 rows); jg = blk>>3 = dim-group 0..31 (8 dims).
// Waves 0-1 = FORWARD, waves 2-3 = BACKWARD; each wave: 4 dims x 8 rows,
// own direction's W register-resident (64 VGPR) — no L2 W-reload.
//
// Per step (ONE publish/consume edge, full-step slack):
//   stage verified h(gs-1) [both dirs] -> LDS; barrier;
//   gemv8 (own dir) -> cell -> publish (h,tag gs+1) fire-and-forget;
//   issue next loads (h(gs), published by peers this step) -> verify tags
//   (steady-state: first try, round-trip hidden by skew+compute); barrier.
// Tag protocol / parity / memset-0 init / transitive overwrite-safety:
// verbatim R7, re-derived for merged schedule (publish(tag t+1) is preceded
// by block-collective barrier after verify(tag t); verified tag t from all
// peers => all peers consumed tag t-1).
// ============================================================
__global__ __launch_bounds__(256, 1) void lstm_kernel(
    const float* __restrict__ Pf, const float* __restrict__ Pb,
    const float* __restrict__ Wf_hh, const float* __restrict__ Wb_hh,
    const int* __restrict__ lengths,
    float* __restrict__ HF, float* __restrict__ HB,
    unsigned long long* __restrict__ hx2,  // [parity][dir][rg8][dim 256][row 8] u64
    float* __restrict__ cbuf,              // [dir][dim 256][row 64]
    int step0, int nsteps)
{
    __shared__ float lds[LDS_FLOATS];    // [0..LDSF) = fwd h, [LDSF..) = bwd h
    const int blk  = blockIdx.x;
    const int rg   = blk & 7;            // row-group (XCD residue)
    const int jg   = blk >> 3;           // dim-group 0..31
    const int tid  = threadIdx.x;
    const int w    = tid >> 6;           // wave 0..3
    const int dirw = w >> 1;             // 0 = fwd (waves 0,1), 1 = bwd (waves 2,3)
    const int wh   = w & 1;              // dim half within this direction
    const int lane = tid & 63;
    const int d    = lane >> 4;          // dim-within-wave 0..3
    const int s    = lane & 15;          // k-slice 0..15
    const int rs   = s & 7;              // owned row 0..7 (dup at s, s+8)
    const int dg   = jg * 8 + wh * 4 + d;     // global dim 0..255
    const int grow = rg * RPBF + rs;          // global batch row
    const int kb   = tid >> 3;           // stage role: dim base 0..31
    const int rr   = tid & 7;            // stage role: row 0..7

    const float* Whh = dirw ? Wb_hh : Wf_hh;
    const float* P   = dirw ? Pb : Pf;
    float* Hout      = dirw ? HB : HF;
    const int len    = lengths[grow];

    // ---- own direction's W_hh slice -> registers (64 VGPR, truly resident)
    float4 wR[4][4];
    #pragma unroll
    for (int g = 0; g < 4; ++g) {
        const float* wrow = Whh + (size_t)(g * HD + dg) * HD + 4 * s;
        #pragma unroll
        for (int q = 0; q < 4; ++q)
            wR[g][q] = *(const float4*)(wrow + 64 * q);
    }

    // ---- cell state (own direction only)
    float c0 = cbuf[((size_t)dirw * HD + dg) * BB + grow];

    // ---- prologue: load + verify BOTH dirs h(step0-1) (tag step0, parity (step0+1)&1)
    unsigned long long hF[8], hB[8];
    {
        const unsigned long long* s0F = hx2 + ((size_t)(((step0 + 1) & 1) * 2 + 0) * RGC + rg) * HXS;
        const unsigned long long* s0B = hx2 + ((size_t)(((step0 + 1) & 1) * 2 + 1) * RGC + rg) * HXS;
        #pragma unroll
        for (int it = 0; it < 8; ++it) {
            hF[it] = ldg_llc_u64(&s0F[(kb + 32 * it) * 8 + rr]);
            hB[it] = ldg_llc_u64(&s0B[(kb + 32 * it) * 8 + rr]);
        }
        #pragma unroll
        for (int it = 0; it < 8; ++it) {
            unsigned long long v = hF[it];
            if ((int)(v >> 32) != step0) {
                const unsigned long long* a = &s0F[(kb + 32 * it) * 8 + rr];
                do { v = ldg_llc_u64(a); } while ((int)(v >> 32) != step0);
            }
            hF[it] = v;
            v = hB[it];
            if ((int)(v >> 32) != step0) {
                const unsigned long long* a = &s0B[(kb + 32 * it) * 8 + rr];
                do { v = ldg_llc_u64(a); } while ((int)(v >> 32) != step0);
            }
            hB[it] = v;
        }
    }

    for (int u = 0; u < nsteps; ++u) {
        const int gs   = step0 + u;
        const int pbt  = TT - 1 - gs;    // original time index for bwd
        const int p    = dirw ? pbt : gs;
        const int slot = dirw ? (nsteps - 1 - u) : u;

        // P terms (own dir, h-independent), issued early
        const float* Pp = P + ((size_t)slot * BB + grow) * NG + dg;
        const float pi = Pp[0], pf = Pp[256], pg = Pp[512], po = Pp[768];

        // stage verified h(gs-1), both dirs -> LDS
        #pragma unroll
        for (int it = 0; it < 8; ++it) {
            lds[rr * HS + kb + 32 * it] =
                __uint_as_float((unsigned)(hF[it] & 0xffffffffull));
            lds[LDSF + rr * HS + kb + 32 * it] =
                __uint_as_float((unsigned)(hB[it] & 0xffffffffull));
        }
        __syncthreads();

        // GEMV (own direction, W register-resident)
        float res[4];
        gemv8(dirw ? (lds + LDSF) : lds, wR, s, res);

        // cell math (one row, one dim, own dir)
        const float ig = 1.f / (1.f + expf(-(res[0] + pi)));
        const float fg = 1.f / (1.f + expf(-(res[1] + pf)));
        const float og = 1.f / (1.f + expf(-(res[3] + po)));
        const float gt = tanhf(res[2] + pg);
        float cn = fg * c0 + ig * gt;
        float hn = og * tanhf(cn);
        if (dirw) {                      // bwd rows inactive until p < len
            const bool v0 = (pbt < len);
            c0 = v0 ? cn : c0;  hn = v0 ? hn : 0.f;
        } else {
            c0 = cn;
        }

        // publish (h, tag gs+1), fire-and-forget; lazy H write
        if (s < 8) {
            stg_llc_u64(&hx2[((size_t)((gs & 1) * 2 + dirw) * RGC + rg) * HXS
                             + (size_t)dg * 8 + rs], pack_ht(hn, gs + 1));
            Hout[((size_t)p * HD + dg) * BB + grow] = hn;
        }

        // issue + verify next step's h(gs) (tag gs+1, parity gs&1), both dirs
        if (u + 1 < nsteps) {
            const unsigned long long* sF = hx2 + ((size_t)((gs & 1) * 2 + 0) * RGC + rg) * HXS;
            const unsigned long long* sB = hx2 + ((size_t)((gs & 1) * 2 + 1) * RGC + rg) * HXS;
            #pragma unroll
            for (int it = 0; it < 8; ++it) {
                hF[it] = ldg_llc_u64(&sF[(kb + 32 * it) * 8 + rr]);
                hB[it] = ldg_llc_u64(&sB[(kb + 32 * it) * 8 + rr]);
            }
            #pragma unroll
            for (int it = 0; it < 8; ++it) {
                unsigned long long v = hF[it];
                if ((int)(v >> 32) != gs + 1) {
                    const unsigned long long* a = &sF[(kb + 32 * it) * 8 + rr];
                    do { v = ldg_llc_u64(a); } while ((int)(v >> 32) != gs + 1);
                }
                hF[it] = v;
                v = hB[it];
                if ((int)(v >> 32) != gs + 1) {
                    const unsigned long long* a = &sB[(kb + 32 * it) * 8 + rr];
                    do { v = ldg_llc_u64(a); } while ((int)(v >> 32) != gs + 1);
                }
                hB[it] = v;
            }
        }
        __syncthreads();   // LDS hazard (stage(u+1) vs GEMV(u)) + collective verify
    }

    if (s < 8)
        cbuf[((size_t)dirw * HD + dg) * BB + grow] = c0;
}

// ============================================================
// K3: emissions = [hf|hb] @ W_out^T + b_out -> emis[t][b][20]
// H layout [t][d][b].  (unchanged, proven)
// ============================================================
__global__ __launch_bounds__(256) void emis_kernel(
    const float* __restrict__ HF, const float* __restrict__ HB,
    const float* __restrict__ W_out, const float* __restrict__ b_out,
    float* __restrict__ emis)
{
    const int t = blockIdx.x;
    const int b = threadIdx.x & 63;
    int jg = threadIdx.x >> 6;
    jg = __builtin_amdgcn_readfirstlane(jg);

    float acc[5];
    #pragma unroll
    for (int u = 0; u < 5; ++u) acc[u] = b_out[jg + 4 * u];

    const float* hf = HF + (size_t)t * HD * BB + b;
    const float* hb = HB + (size_t)t * HD * BB + b;
    for (int k = 0; k < HD; ++k) {
        const float hv = hf[(size_t)k * BB];
        #pragma unroll
        for (int u = 0; u < 5; ++u)
            acc[u] = fmaf(hv, W_out[(size_t)(jg + 4 * u) * 512 + k], acc[u]);
    }
    for (int k = 0; k < HD; ++k) {
        const float hv = hb[(size_t)k * BB];
        #pragma unroll
        for (int u = 0; u < 5; ++u)
            acc[u] = fmaf(hv, W_out[(size_t)(jg + 4 * u) * 512 + HD + k], acc[u]);
    }
    #pragma unroll
    for (int u = 0; u < 5; ++u)
        emis[((size_t)t * BB + b) * KK + jg + 4 * u] = acc[u];
}

// ============================================================
// K4: Viterbi per batch row; exact first-max argmax; bp in LDS. (unchanged)
// ============================================================
__global__ __launch_bounds__(64) void viterbi_kernel(
    const float* __restrict__ emis, const int* __restrict__ lengths,
    const float* __restrict__ trans, const int* __restrict__ stop_id_p,
    float* __restrict__ out)
{
    __shared__ float tr[KK * KK];
    __shared__ float delta[KK], nd[KK];
    __shared__ unsigned char bp[TT][KK];
    const int b = blockIdx.x;
    const int tid = threadIdx.x;
    for (int i = tid; i < KK * KK; i += 64) tr[i] = trans[i];
    if (tid < KK) delta[tid] = 0.f;
    const int len = lengths[b];
    __syncthreads();

    for (int t = 0; t < TT; ++t) {
        if (tid < KK) {
            if (t < len) {
                float best = delta[0] + tr[tid * KK + 0];
                int am = 0;
                for (int p2 = 1; p2 < KK; ++p2) {
                    const float v = delta[p2] + tr[tid * KK + p2];
                    if (v > best) { best = v; am = p2; }
                }
                nd[tid] = best + emis[((size_t)t * BB + b) * KK + tid];
                bp[t][tid] = (unsigned char)am;
            } else {
                nd[tid] = delta[tid];
                bp[t][tid] = (unsigned char)tid;
            }
        }
        __syncthreads();
        if (tid < KK) delta[tid] = nd[tid];
        __syncthreads();
    }

    if (tid == 0) {
        const int stop_id = *stop_id_p;
        float best = delta[0] + tr[stop_id * KK + 0];
        int bl = 0;
        for (int jx = 1; jx < KK; ++jx) {
            const float v = delta[jx] + tr[stop_id * KK + jx];
            if (v > best) { best = v; bl = jx; }
        }
        out[b] = best;
        float* pout = out + BB + (size_t)b * (TT + 1);
        pout[TT] = (float)bl;
        int tag = bl;
        for (int t = TT - 1; t >= 0; --t) {
            tag = bp[t][tag];
            pout[t] = (float)tag;
        }
    }
}

// ============================================================
extern "C" void kernel_launch(void* const* d_in, const int* in_sizes, int n_in,
                              void* d_out, int out_size, void* d_ws, size_t ws_size,
                              hipStream_t stream) {
    const int*   sentence = (const int*)d_in[0];
    const int*   lengths  = (const int*)d_in[1];
    const int*   stop_id  = (const int*)d_in[3];
    const float* embed    = (const float*)d_in[4];
    const float* Wf_ih    = (const float*)d_in[5];
    const float* Wf_hh    = (const float*)d_in[6];
    const float* bf       = (const float*)d_in[7];
    const float* Wb_ih    = (const float*)d_in[8];
    const float* Wb_hh    = (const float*)d_in[9];
    const float* bb       = (const float*)d_in[10];
    const float* W_out    = (const float*)d_in[11];
    const float* b_out    = (const float*)d_in[12];
    const float* trans    = (const float*)d_in[13];
    float* out = (float*)d_out;

    const size_t hf_elems   = (size_t)TT * HD * BB;
    const size_t emis_elems = (size_t)TT * BB * KK;
    const size_t hx_u64     = (size_t)2 * 2 * RGC * HD * RPBF; // 65536 u64
    const size_t cbuf_elems = (size_t)2 * HD * BB;             // 32768
    const size_t fixed_bytes = (2 * hf_elems + emis_elems + cbuf_elems) * 4 + hx_u64 * 8;

    int CH = 0;
    const int cands[6] = {256, 128, 64, 32, 16, 8};
    for (int i = 0; i < 6; ++i) {
        const size_t need = fixed_bytes + 2ull * cands[i] * BB * NG * 4;
        if (need <= ws_size) { CH = cands[i]; break; }
    }
    if (CH == 0) return;

    float* Pf    = (float*)d_ws;
    float* Pb    = Pf + (size_t)CH * BB * NG;
    float* HF    = Pb + (size_t)CH * BB * NG;
    float* HB    = HF + hf_elems;
    float* emis  = HB + hf_elems;
    unsigned long long* hx2 = (unsigned long long*)(emis + emis_elems); // 8B-aligned (even float offset)
    float* cbuf  = (float*)(hx2 + hx_u64);

    // zero hx2 (tags 0 == valid initial h(-1)) + cbuf — contiguous region
    hipMemsetAsync(hx2, 0, hx_u64 * 8 + cbuf_elems * 4, stream);

    const int nch = TT / CH;
    for (int c = 0; c < nch; ++c) {
        const int t0f = c * CH;
        const int t0b = TT - (c + 1) * CH;
        proj_kernel<<<dim3(CH, 32), 256, 0, stream>>>(
            sentence, embed, Wf_ih, bf, Wb_ih, bb, Pf, Pb, t0f, t0b);
        lstm_kernel<<<dim3(256), 256, 0, stream>>>(
            Pf, Pb, Wf_hh, Wb_hh, lengths, HF, HB, hx2, cbuf, c * CH, CH);
    }
    emis_kernel<<<dim3(TT), 256, 0, stream>>>(HF, HB, W_out, b_out, emis);
    viterbi_kernel<<<dim3(BB), 64, 0, stream>>>(emis, lengths, trans, stop_id, out);
}